// Round 1
// baseline (1159.663 us; speedup 1.0000x reference)
//
#include <hip/hip_runtime.h>
#include <math.h>

// Problem constants: b=4, C=256, H=W=64
#define NPOS 4096            // 64*64 spatial positions
#define CPB  1048576         // C*NPOS, per-batch stride in q/k/v/att
// ws layout (float offsets)
#define QOFF  ((size_t)0)
#define KOFF  ((size_t)4194304)
#define VOFF  ((size_t)8388608)
#define AOFF  ((size_t)12582912)
#define S0OFF ((size_t)16777216)                  // 4*64*64
#define S1OFF (S0OFF + (size_t)4*64*64)           // 4*256*256
#define S2OFF (S1OFF + (size_t)4*256*256)         // 4*1024*1024
#define WTOFF (S2OFF + (size_t)4*1024*1024)       // 256*9*256 transposed Wo

// ---------------------------------------------------------------------------
// Kernel 1: fused QKV 1x1-conv projections.  out_t[b][o][p] = sum_c W_t[o][c] x[b][c][p] + bias_t[o]
// grid (64 ntile, 4 mtile, 12 = b*3+t), 256 threads, 64x64 tile, 4x4 microtile, BK=16
__global__ __launch_bounds__(256) void qkv_gemm(
    const float* __restrict__ x,
    const float* __restrict__ Wq, const float* __restrict__ Wk, const float* __restrict__ Wv,
    const float* __restrict__ bq, const float* __restrict__ bk, const float* __restrict__ bv,
    float* __restrict__ ws) {
  int b = blockIdx.z / 3, t = blockIdx.z % 3;
  const float* W    = (t == 0) ? Wq : (t == 1) ? Wk : Wv;
  const float* bias = (t == 0) ? bq : (t == 1) ? bk : bv;
  float* outp = ws + (size_t)t * 4194304 + (size_t)b * CPB;
  int o0 = blockIdx.y * 64, p0 = blockIdx.x * 64;
  __shared__ float As[16][64];   // [k][m]
  __shared__ float Bs[16][64];   // [k][n]
  int tid = threadIdx.x;
  int ti = tid >> 4, tj = tid & 15;
  int lm = tid & 63, lg = tid >> 6;
  float acc[4][4] = {};
  for (int k0 = 0; k0 < 256; k0 += 16) {
    float4 av = *(const float4*)&W[(size_t)(o0 + lm) * 256 + k0 + lg * 4];
    As[lg * 4 + 0][lm] = av.x; As[lg * 4 + 1][lm] = av.y;
    As[lg * 4 + 2][lm] = av.z; As[lg * 4 + 3][lm] = av.w;
    for (int r = 0; r < 4; ++r)
      Bs[lg * 4 + r][lm] = x[(size_t)b * CPB + (size_t)(k0 + lg * 4 + r) * NPOS + p0 + lm];
    __syncthreads();
#pragma unroll
    for (int kk = 0; kk < 16; ++kk) {
      float4 a4 = *(const float4*)&As[kk][ti * 4];
      float4 b4 = *(const float4*)&Bs[kk][tj * 4];
      const float* ap = &a4.x; const float* bp = &b4.x;
#pragma unroll
      for (int i = 0; i < 4; ++i)
#pragma unroll
        for (int j = 0; j < 4; ++j) acc[i][j] += ap[i] * bp[j];
    }
    __syncthreads();
  }
#pragma unroll
  for (int i = 0; i < 4; ++i) {
    float bi = bias[o0 + ti * 4 + i];
    float4 st = make_float4(acc[i][0] + bi, acc[i][1] + bi, acc[i][2] + bi, acc[i][3] + bi);
    *(float4*)&outp[(size_t)(o0 + ti * 4 + i) * NPOS + p0 + tj * 4] = st;
  }
}

// ---------------------------------------------------------------------------
// Token-tile loader for score kernels: dims [d0,d0+16) x tokens [t0,t0+64) -> T[dc*72 + tl]
// Token t=(po*OW+qo), dim d=(c*PH*PW + y*PW + x); global rows (c, po*PH+y) are 64-float
// contiguous w-rows -> fully coalesced loads.
template<int PH, int PW>
__device__ __forceinline__ void load_qk_tile(const float* __restrict__ base, int d0, int t0,
                                             float* __restrict__ T) {
  const int PP = PH * PW, OW = 64 / PW;
  const int NPO = 64 / OW;                       // po-rows spanned by 64 tokens
  const int NY  = (PP >= 16) ? (16 / PW) : PH;   // y values in one 16-dim chunk
  int w = threadIdx.x & 63, rg = threadIdx.x >> 6;
  int qo = w / PW, x = w % PW;
  int pbase = t0 / OW;
  int cbase = d0 / PP;
  int ybase = (PP >= 16) ? ((d0 % PP) / PW) : 0;
#pragma unroll
  for (int rr = 0; rr < 4; ++rr) {
    int r  = rg * 4 + rr;                        // 16 rows total
    int pi = r % NPO; int t1 = r / NPO; int yi = t1 % NY; int ci = t1 / NY;
    int c = cbase + ci, y = ybase + yi, po = pbase + pi;
    float v = base[(size_t)c * NPOS + (po * PH + y) * 64 + qo * PW + x];
    T[(ci * PP + yi * PW + x) * 72 + pi * OW + qo] = v;
  }
}

// Scores for heads 0..2: S[b][i][j] = scale * <q_i, k_j>.  grid (4, (N/64)^2, NSLICE)
template<int HEAD, int PH, int PW, int NSLICE>
__global__ __launch_bounds__(256) void score_kernel(const float* __restrict__ ws_,
                                                    float* __restrict__ Sh) {
  const int OW = 64 / PW, OH = 64 / PH, N = OH * OW, D = 64 * PH * PW;
  int b = blockIdx.x;
  const int nt = N / 64;
  int it = blockIdx.y / nt, jt = blockIdx.y % nt;
  const float* qb = ws_ + QOFF + (size_t)b * CPB + (size_t)HEAD * 64 * NPOS;
  const float* kb = ws_ + KOFF + (size_t)b * CPB + (size_t)HEAD * 64 * NPOS;
  float* S = Sh + (size_t)b * N * N;
  __shared__ float Qs[16 * 72], Ks[16 * 72];
  int tid = threadIdx.x, ti = tid >> 4, tj = tid & 15;
  float acc[4][4] = {};
  const int dlen = D / NSLICE;
  int dstart = blockIdx.z * dlen;
  for (int d0 = dstart; d0 < dstart + dlen; d0 += 16) {
    load_qk_tile<PH, PW>(qb, d0, it * 64, Qs);
    load_qk_tile<PH, PW>(kb, d0, jt * 64, Ks);
    __syncthreads();
#pragma unroll
    for (int kk = 0; kk < 16; ++kk) {
      float4 a4 = *(const float4*)&Qs[kk * 72 + ti * 4];
      float4 b4 = *(const float4*)&Ks[kk * 72 + tj * 4];
      const float* ap = &a4.x; const float* bp = &b4.x;
#pragma unroll
      for (int i = 0; i < 4; ++i)
#pragma unroll
        for (int j = 0; j < 4; ++j) acc[i][j] += ap[i] * bp[j];
    }
    __syncthreads();
  }
  float scale = rsqrtf((float)D);
  if (NSLICE == 1) {
#pragma unroll
    for (int i = 0; i < 4; ++i) {
      float4 st = make_float4(acc[i][0] * scale, acc[i][1] * scale,
                              acc[i][2] * scale, acc[i][3] * scale);
      *(float4*)&S[(size_t)(it * 64 + ti * 4 + i) * N + jt * 64 + tj * 4] = st;
    }
  } else {
#pragma unroll
    for (int i = 0; i < 4; ++i)
#pragma unroll
      for (int j = 0; j < 4; ++j)
        atomicAdd(&S[(size_t)(it * 64 + ti * 4 + i) * N + jt * 64 + tj * 4 + j],
                  acc[i][j] * scale);
  }
}

// Row softmax in place. grid = rows, block 256.
__global__ __launch_bounds__(256) void softmax_kernel(float* __restrict__ Sh, int N) {
  float* row = Sh + (size_t)blockIdx.x * N;
  __shared__ float red[4];
  int tid = threadIdx.x;
  float m = -3.0e38f;
  for (int j = tid; j < N; j += 256) m = fmaxf(m, row[j]);
#pragma unroll
  for (int d = 32; d >= 1; d >>= 1) m = fmaxf(m, __shfl_xor(m, d));
  if ((tid & 63) == 0) red[tid >> 6] = m;
  __syncthreads();
  m = fmaxf(fmaxf(red[0], red[1]), fmaxf(red[2], red[3]));
  __syncthreads();  // all reads of red done before reuse
  float s = 0.f;
  for (int j = tid; j < N; j += 256) { float e = __expf(row[j] - m); row[j] = e; s += e; }
#pragma unroll
  for (int d = 32; d >= 1; d >>= 1) s += __shfl_xor(s, d);
  if ((tid & 63) == 0) red[tid >> 6] = s;
  __syncthreads();
  s = red[0] + red[1] + red[2] + red[3];
  float inv = 1.0f / s;
  for (int j = tid; j < N; j += 256) row[j] *= inv;
}

// V-tile loader for PV: tokens [t0,t0+16) x dims [d0,d0+64) -> T[jj*68 + dd]
template<int PH, int PW>
__device__ __forceinline__ void load_v_tile(const float* __restrict__ base, int d0, int t0,
                                            float* __restrict__ T) {
  const int PP = PH * PW, OW = 64 / PW;
  const int TPR   = (OW < 16) ? OW : 16;    // tokens per po-row in tile
  const int WIDTH = TPR * PW;               // 64 or 32
  const int RPP   = 256 / WIDTH;            // rows per pass
  const int NPO   = 16 / TPR;
  int lw = threadIdx.x % WIDTH, rg = threadIdx.x / WIDTH;
  int cbase = d0 / PP;
  int pbase = t0 / OW, qbase = t0 % OW;
  int qo = lw / PW, x = lw % PW;
#pragma unroll
  for (int rr = 0; rr < 4; ++rr) {
    int r  = rg + RPP * rr;
    int pi = r % NPO; int t1 = r / NPO; int y = t1 % PH; int ci = t1 / PH;
    float v = base[(size_t)(cbase + ci) * NPOS + ((pbase + pi) * PH + y) * 64 + (qbase + qo) * PW + x];
    T[(pi * TPR + qo) * 68 + ci * PP + y * PW + x] = v;
  }
}

// PV for heads 0..2: att[tok][d] = sum_j P[tok][j] V[j][d], scattered back to [c][h][w].
// grid (4, (N/64) * (D/64))
template<int HEAD, int PH, int PW>
__global__ __launch_bounds__(256) void pv_kernel(const float* __restrict__ ws_,
                                                 const float* __restrict__ Sh,
                                                 float* __restrict__ att) {
  const int OW = 64 / PW, N = (64 / PH) * OW, D = 64 * PH * PW, PP = PH * PW;
  const int NDC = D / 64;
  int b = blockIdx.x;
  int it = blockIdx.y / NDC, dt = blockIdx.y % NDC;
  int d0 = dt * 64, i0 = it * 64;
  const float* vb = ws_ + VOFF + (size_t)b * CPB + (size_t)HEAD * 64 * NPOS;
  const float* P  = Sh + (size_t)b * N * N;
  float* ab = att + (size_t)b * CPB + (size_t)HEAD * 64 * NPOS;
  __shared__ float Ps[16 * 68];  // [jj][i]
  __shared__ float Vs[16 * 68];  // [jj][dd]
  int tid = threadIdx.x, ti = tid >> 4, tj = tid & 15;
  int pj = tid & 15, pib = tid >> 4;
  float acc[4][4] = {};
  for (int j0 = 0; j0 < N; j0 += 16) {
#pragma unroll
    for (int rr = 0; rr < 4; ++rr)
      Ps[pj * 68 + pib + 16 * rr] = P[(size_t)(i0 + pib + 16 * rr) * N + j0 + pj];
    load_v_tile<PH, PW>(vb, d0, j0, Vs);
    __syncthreads();
#pragma unroll
    for (int jj = 0; jj < 16; ++jj) {
      float4 p4 = *(const float4*)&Ps[jj * 68 + ti * 4];
      float4 v4 = *(const float4*)&Vs[jj * 68 + tj * 4];
      const float* pp = &p4.x; const float* vp = &v4.x;
#pragma unroll
      for (int i = 0; i < 4; ++i)
#pragma unroll
        for (int j = 0; j < 4; ++j) acc[i][j] += pp[i] * vp[j];
    }
    __syncthreads();
  }
#pragma unroll
  for (int i = 0; i < 4; ++i) {
    int tok = i0 + ti * 4 + i;
    int po = tok / OW, qo = tok % OW;
#pragma unroll
    for (int j = 0; j < 4; ++j) {
      int d = d0 + tj * 4 + j;
      int c = d / PP, rem = d % PP, y = rem / PW, x = rem % PW;
      ab[(size_t)c * NPOS + (po * PH + y) * 64 + qo * PW + x] = acc[i][j];
    }
  }
}

// ---------------------------------------------------------------------------
// Head 3 (1x1 patches): flash attention, n=4096, d=64, channel-major layout throughout.
// grid (4, 64): one 64-query tile per block.
__global__ __launch_bounds__(256) void flash_head3(const float* __restrict__ ws_,
                                                   float* __restrict__ att) {
  int b = blockIdx.x; int q0 = blockIdx.y * 64;
  const float* qb = ws_ + QOFF + (size_t)b * CPB + (size_t)192 * NPOS;
  const float* kb = ws_ + KOFF + (size_t)b * CPB + (size_t)192 * NPOS;
  const float* vb = ws_ + VOFF + (size_t)b * CPB + (size_t)192 * NPOS;
  float* ab = att + (size_t)b * CPB + (size_t)192 * NPOS;
  __shared__ float Qs[64 * 68];  // [ch][pos]
  __shared__ float Ks[64 * 68];  // [ch][pos]; reused as Ps = [kj][qi] after S phase
  __shared__ float Vs[64 * 68];  // [pos][ch] (transposed at load)
  float* Psh = Ks;
  int tid = threadIdx.x, ti = tid >> 4, tj = tid & 15;
  int lp = tid & 63, lg = tid >> 6;
#pragma unroll
  for (int rr = 0; rr < 16; ++rr) {
    int c = lg * 16 + rr;
    Qs[c * 68 + lp] = qb[(size_t)c * NPOS + q0 + lp];
  }
  float mrow[4] = {-3.0e38f, -3.0e38f, -3.0e38f, -3.0e38f};
  float lrow[4] = {0.f, 0.f, 0.f, 0.f};
  float accd[4][4] = {};  // [jd = channel][iq = query]
  for (int kt = 0; kt < 4096; kt += 64) {
    __syncthreads();  // prev PV reads of Ps/Vs done (also covers Q-load on iter 0)
#pragma unroll
    for (int rr = 0; rr < 16; ++rr) {
      int c = lg * 16 + rr;
      float kvv = kb[(size_t)c * NPOS + kt + lp];
      float vvv = vb[(size_t)c * NPOS + kt + lp];
      Ks[c * 68 + lp] = kvv;
      Vs[lp * 68 + c] = vvv;
    }
    __syncthreads();
    float s[4][4] = {};
#pragma unroll 8
    for (int c = 0; c < 64; ++c) {
      float4 a4 = *(const float4*)&Qs[c * 68 + ti * 4];
      float4 b4 = *(const float4*)&Ks[c * 68 + tj * 4];
      const float* ap = &a4.x; const float* bp = &b4.x;
#pragma unroll
      for (int i = 0; i < 4; ++i)
#pragma unroll
        for (int j = 0; j < 4; ++j) s[i][j] += ap[i] * bp[j];
    }
#pragma unroll
    for (int i = 0; i < 4; ++i) {
      float tm = fmaxf(fmaxf(s[i][0] * 0.125f, s[i][1] * 0.125f),
                       fmaxf(s[i][2] * 0.125f, s[i][3] * 0.125f));
#pragma unroll
      for (int d = 8; d >= 1; d >>= 1) tm = fmaxf(tm, __shfl_xor(tm, d));
      float mnew = fmaxf(mrow[i], tm);
      float f = __expf(mrow[i] - mnew);
      float rs = 0.f;
#pragma unroll
      for (int j = 0; j < 4; ++j) {
        s[i][j] = __expf(s[i][j] * 0.125f - mnew);
        rs += s[i][j];
      }
#pragma unroll
      for (int d = 8; d >= 1; d >>= 1) rs += __shfl_xor(rs, d);
      lrow[i] = lrow[i] * f + rs;
      mrow[i] = mnew;
#pragma unroll
      for (int jd = 0; jd < 4; ++jd) accd[jd][i] *= f;
    }
    __syncthreads();  // S-phase reads of Ks done before P overwrite
#pragma unroll
    for (int i = 0; i < 4; ++i)
#pragma unroll
      for (int j = 0; j < 4; ++j)
        Psh[(tj * 4 + j) * 68 + ti * 4 + i] = s[i][j];
    __syncthreads();  // P ready
#pragma unroll 8
    for (int jj = 0; jj < 64; ++jj) {
      float4 p4 = *(const float4*)&Psh[jj * 68 + ti * 4];
      float4 v4 = *(const float4*)&Vs[jj * 68 + tj * 4];
      const float* pp = &p4.x; const float* vp = &v4.x;
#pragma unroll
      for (int jd = 0; jd < 4; ++jd)
#pragma unroll
        for (int iq = 0; iq < 4; ++iq) accd[jd][iq] += vp[jd] * pp[iq];
    }
  }
  float inv[4];
#pragma unroll
  for (int i = 0; i < 4; ++i) inv[i] = 1.0f / lrow[i];
#pragma unroll
  for (int jd = 0; jd < 4; ++jd) {
    float4 st = make_float4(accd[jd][0] * inv[0], accd[jd][1] * inv[1],
                            accd[jd][2] * inv[2], accd[jd][3] * inv[3]);
    *(float4*)&ab[(size_t)(tj * 4 + jd) * NPOS + q0 + ti * 4] = st;
  }
}

// ---------------------------------------------------------------------------
// Wo [o][c][ky][kx] -> Wot [(c*9+k)][o] for coalesced conv weight staging.
__global__ __launch_bounds__(256) void transpose_wo(const float* __restrict__ Wo,
                                                    float* __restrict__ Wot) {
  int idx = blockIdx.x * 256 + threadIdx.x;  // 2304*256 total
  int o = idx & 255, ck = idx >> 8;
  Wot[idx] = Wo[(size_t)o * 2304 + ck];
}

// 3x3 SAME conv + BN(running stats) + LeakyReLU(0.2).  grid (64 h, 4 otile, 4 b).
__global__ __launch_bounds__(256) void conv_bn_lrelu(
    const float* __restrict__ att, const float* __restrict__ Wot,
    const float* __restrict__ bo, const float* __restrict__ gamma,
    const float* __restrict__ beta, const float* __restrict__ rmean,
    const float* __restrict__ rvar, float* __restrict__ out) {
  int h = blockIdx.x, ot = blockIdx.y, b = blockIdx.z;
  int o0 = ot * 64;
  __shared__ float Ws[144 * 64];   // [(cc*9 + k)][o]
  __shared__ float As[48 * 68];    // [(cc*3 + dy)][w: -1..64 at +1]
  int tid = threadIdx.x, to = tid >> 4, tw = tid & 15;
  int lw = tid & 63, lg = tid >> 6;
  float acc[4][4] = {};
  for (int c0 = 0; c0 < 256; c0 += 16) {
    for (int rr = 0; rr < 36; ++rr) {
      int r = lg + 4 * rr;  // 0..143
      Ws[r * 64 + lw] = Wot[(size_t)(c0 * 9 + r) * 256 + o0 + lw];
    }
    for (int rr = 0; rr < 12; ++rr) {
      int r = lg + 4 * rr;  // 0..47
      int cc = r / 3, dy = r % 3, hh = h + dy - 1;
      float v = (hh >= 0 && hh < 64)
                    ? att[(size_t)b * CPB + (size_t)(c0 + cc) * NPOS + hh * 64 + lw] : 0.f;
      As[r * 68 + 1 + lw] = v;
    }
    if (tid < 48) { As[tid * 68] = 0.f; As[tid * 68 + 65] = 0.f; }
    __syncthreads();
    for (int cc = 0; cc < 16; ++cc) {
#pragma unroll
      for (int dy = 0; dy < 3; ++dy) {
        int ar = (cc * 3 + dy) * 68;
        float4 alo = *(const float4*)&As[ar + tw * 4];
        float4 ahi = *(const float4*)&As[ar + tw * 4 + 4];
        float a[8] = {alo.x, alo.y, alo.z, alo.w, ahi.x, ahi.y, ahi.z, ahi.w};
#pragma unroll
        for (int dx = 0; dx < 3; ++dx) {
          float4 wv = *(const float4*)&Ws[(cc * 9 + dy * 3 + dx) * 64 + to * 4];
          const float* wp = &wv.x;
#pragma unroll
          for (int i = 0; i < 4; ++i)
#pragma unroll
            for (int j = 0; j < 4; ++j) acc[i][j] += wp[i] * a[j + dx];
        }
      }
    }
    __syncthreads();
  }
#pragma unroll
  for (int i = 0; i < 4; ++i) {
    int oc = o0 + to * 4 + i;
    float g  = gamma[oc] * rsqrtf(rvar[oc] + 1e-5f);
    float bb = beta[oc] - rmean[oc] * g;
    float bias = bo[oc];
    float4 st;
    float* sp = &st.x;
#pragma unroll
    for (int j = 0; j < 4; ++j) {
      float z = (acc[i][j] + bias) * g + bb;
      sp[j] = (z >= 0.f) ? z : 0.2f * z;
    }
    *(float4*)&out[(size_t)b * CPB + (size_t)oc * NPOS + h * 64 + tw * 4] = st;
  }
}

// ---------------------------------------------------------------------------
extern "C" void kernel_launch(void* const* d_in, const int* in_sizes, int n_in,
                              void* d_out, int out_size, void* d_ws, size_t ws_size,
                              hipStream_t stream) {
  (void)in_sizes; (void)n_in; (void)out_size; (void)ws_size;
  const float* x     = (const float*)d_in[0];
  const float* Wq    = (const float*)d_in[1];
  const float* bq    = (const float*)d_in[2];
  const float* Wk    = (const float*)d_in[3];
  const float* bk    = (const float*)d_in[4];
  const float* Wv    = (const float*)d_in[5];
  const float* bv    = (const float*)d_in[6];
  const float* Wo    = (const float*)d_in[7];
  const float* bo    = (const float*)d_in[8];
  const float* gamma = (const float*)d_in[9];
  const float* beta  = (const float*)d_in[10];
  const float* rmean = (const float*)d_in[11];
  const float* rvar  = (const float*)d_in[12];
  float* ws  = (float*)d_ws;
  float* out = (float*)d_out;

  hipMemsetAsync(ws + S0OFF, 0, (size_t)4 * 64 * 64 * sizeof(float), stream);
  transpose_wo<<<2304, 256, 0, stream>>>(Wo, ws + WTOFF);
  qkv_gemm<<<dim3(64, 4, 12), 256, 0, stream>>>(x, Wq, Wk, Wv, bq, bk, bv, ws);

  score_kernel<0, 8, 8, 8><<<dim3(4, 1, 8),   256, 0, stream>>>(ws, ws + S0OFF);
  score_kernel<1, 4, 4, 1><<<dim3(4, 16, 1),  256, 0, stream>>>(ws, ws + S1OFF);
  score_kernel<2, 2, 2, 1><<<dim3(4, 256, 1), 256, 0, stream>>>(ws, ws + S2OFF);

  softmax_kernel<<<4 * 64,   256, 0, stream>>>(ws + S0OFF, 64);
  softmax_kernel<<<4 * 256,  256, 0, stream>>>(ws + S1OFF, 256);
  softmax_kernel<<<4 * 1024, 256, 0, stream>>>(ws + S2OFF, 1024);

  pv_kernel<0, 8, 8><<<dim3(4, 64), 256, 0, stream>>>(ws, ws + S0OFF, ws + AOFF);
  pv_kernel<1, 4, 4><<<dim3(4, 64), 256, 0, stream>>>(ws, ws + S1OFF, ws + AOFF);
  pv_kernel<2, 2, 2><<<dim3(4, 64), 256, 0, stream>>>(ws, ws + S2OFF, ws + AOFF);
  flash_head3<<<dim3(4, 64), 256, 0, stream>>>(ws, ws + AOFF);

  conv_bn_lrelu<<<dim3(64, 4, 4), 256, 0, stream>>>(ws + AOFF, ws + WTOFF, bo, gamma, beta,
                                                    rmean, rvar, out);
}

// Round 3
// 723.409 us; speedup vs baseline: 1.6031x; 1.6031x over previous
//
#include <hip/hip_runtime.h>
#include <math.h>

// Problem constants: b=4, C=256, H=W=64
#define NPOS 4096            // 64*64 spatial positions
#define CPB  1048576         // C*NPOS, per-batch stride in q/k/v
// ws layout (float offsets)
#define QOFF  ((size_t)0)
#define KOFF  ((size_t)4194304)
#define VOFF  ((size_t)8388608)
#define AOFF  ((size_t)12582912)                  // bf16 att, [b][pos][c], 4*4096*256 ushort
#define S0OFF ((size_t)16777216)                  // 4*64*64
#define S1OFF (S0OFF + (size_t)4*64*64)           // 4*256*256
#define S2OFF (S1OFF + (size_t)4*256*256)         // 4*1024*1024
#define WTOFF (S2OFF + (size_t)4*1024*1024)       // bf16 W2 [k][o][c], 9*256*256 ushort

typedef __attribute__((ext_vector_type(8))) short bf16x8;
typedef __attribute__((ext_vector_type(4))) float f32x4;

static __device__ __forceinline__ unsigned short f2bf(float f) {
  union { float f; unsigned u; } v; v.f = f;
  unsigned u = v.u;
  return (unsigned short)((u + 0x7FFFu + ((u >> 16) & 1u)) >> 16);
}

// ---------------------------------------------------------------------------
// Kernel 1: fused QKV 1x1-conv projections (fp32 VALU GEMM).
__global__ __launch_bounds__(256) void qkv_gemm(
    const float* __restrict__ x,
    const float* __restrict__ Wq, const float* __restrict__ Wk, const float* __restrict__ Wv,
    const float* __restrict__ bq, const float* __restrict__ bk, const float* __restrict__ bv,
    float* __restrict__ ws) {
  int b = blockIdx.z / 3, t = blockIdx.z % 3;
  const float* W    = (t == 0) ? Wq : (t == 1) ? Wk : Wv;
  const float* bias = (t == 0) ? bq : (t == 1) ? bk : bv;
  float* outp = ws + (size_t)t * 4194304 + (size_t)b * CPB;
  int o0 = blockIdx.y * 64, p0 = blockIdx.x * 64;
  __shared__ float As[16][64];   // [k][m]
  __shared__ float Bs[16][64];   // [k][n]
  int tid = threadIdx.x;
  int ti = tid >> 4, tj = tid & 15;
  int lm = tid & 63, lg = tid >> 6;
  float acc[4][4] = {};
  for (int k0 = 0; k0 < 256; k0 += 16) {
    float4 av = *(const float4*)&W[(size_t)(o0 + lm) * 256 + k0 + lg * 4];
    As[lg * 4 + 0][lm] = av.x; As[lg * 4 + 1][lm] = av.y;
    As[lg * 4 + 2][lm] = av.z; As[lg * 4 + 3][lm] = av.w;
    for (int r = 0; r < 4; ++r)
      Bs[lg * 4 + r][lm] = x[(size_t)b * CPB + (size_t)(k0 + lg * 4 + r) * NPOS + p0 + lm];
    __syncthreads();
#pragma unroll
    for (int kk = 0; kk < 16; ++kk) {
      float4 a4 = *(const float4*)&As[kk][ti * 4];
      float4 b4 = *(const float4*)&Bs[kk][tj * 4];
      const float* ap = &a4.x; const float* bp = &b4.x;
#pragma unroll
      for (int i = 0; i < 4; ++i)
#pragma unroll
        for (int j = 0; j < 4; ++j) acc[i][j] += ap[i] * bp[j];
    }
    __syncthreads();
  }
#pragma unroll
  for (int i = 0; i < 4; ++i) {
    float bi = bias[o0 + ti * 4 + i];
    float4 st = make_float4(acc[i][0] + bi, acc[i][1] + bi, acc[i][2] + bi, acc[i][3] + bi);
    *(float4*)&outp[(size_t)(o0 + ti * 4 + i) * NPOS + p0 + tj * 4] = st;
  }
}

// ---------------------------------------------------------------------------
// Token-tile loader for score kernels: dims [d0,d0+16) x tokens [t0,t0+64) -> T[dc*72 + tl]
template<int PH, int PW>
__device__ __forceinline__ void load_qk_tile(const float* __restrict__ base, int d0, int t0,
                                             float* __restrict__ T) {
  const int PP = PH * PW, OW = 64 / PW;
  const int NPO = 64 / OW;                       // po-rows spanned by 64 tokens
  const int NY  = (PP >= 16) ? (16 / PW) : PH;   // y values in one 16-dim chunk
  int w = threadIdx.x & 63, rg = threadIdx.x >> 6;
  int qo = w / PW, x = w % PW;
  int pbase = t0 / OW;
  int cbase = d0 / PP;
  int ybase = (PP >= 16) ? ((d0 % PP) / PW) : 0;
#pragma unroll
  for (int rr = 0; rr < 4; ++rr) {
    int r  = rg * 4 + rr;                        // 16 rows total
    int pi = r % NPO; int t1 = r / NPO; int yi = t1 % NY; int ci = t1 / NY;
    int c = cbase + ci, y = ybase + yi, po = pbase + pi;
    float v = base[(size_t)c * NPOS + (po * PH + y) * 64 + qo * PW + x];
    T[(ci * PP + yi * PW + x) * 72 + pi * OW + qo] = v;
  }
}

// Scores for heads 0..2: S[b][i][j] = scale * <q_i, k_j>.  grid (4, (N/64)^2, NSLICE)
template<int HEAD, int PH, int PW, int NSLICE>
__global__ __launch_bounds__(256) void score_kernel(const float* __restrict__ ws_,
                                                    float* __restrict__ Sh) {
  const int OW = 64 / PW, OH = 64 / PH, N = OH * OW, D = 64 * PH * PW;
  int b = blockIdx.x;
  const int nt = N / 64;
  int it = blockIdx.y / nt, jt = blockIdx.y % nt;
  const float* qb = ws_ + QOFF + (size_t)b * CPB + (size_t)HEAD * 64 * NPOS;
  const float* kb = ws_ + KOFF + (size_t)b * CPB + (size_t)HEAD * 64 * NPOS;
  float* S = Sh + (size_t)b * N * N;
  __shared__ float Qs[16 * 72], Ks[16 * 72];
  int tid = threadIdx.x, ti = tid >> 4, tj = tid & 15;
  float acc[4][4] = {};
  const int dlen = D / NSLICE;
  int dstart = blockIdx.z * dlen;
  for (int d0 = dstart; d0 < dstart + dlen; d0 += 16) {
    load_qk_tile<PH, PW>(qb, d0, it * 64, Qs);
    load_qk_tile<PH, PW>(kb, d0, jt * 64, Ks);
    __syncthreads();
#pragma unroll
    for (int kk = 0; kk < 16; ++kk) {
      float4 a4 = *(const float4*)&Qs[kk * 72 + ti * 4];
      float4 b4 = *(const float4*)&Ks[kk * 72 + tj * 4];
      const float* ap = &a4.x; const float* bp = &b4.x;
#pragma unroll
      for (int i = 0; i < 4; ++i)
#pragma unroll
        for (int j = 0; j < 4; ++j) acc[i][j] += ap[i] * bp[j];
    }
    __syncthreads();
  }
  float scale = rsqrtf((float)D);
  if (NSLICE == 1) {
#pragma unroll
    for (int i = 0; i < 4; ++i) {
      float4 st = make_float4(acc[i][0] * scale, acc[i][1] * scale,
                              acc[i][2] * scale, acc[i][3] * scale);
      *(float4*)&S[(size_t)(it * 64 + ti * 4 + i) * N + jt * 64 + tj * 4] = st;
    }
  } else {
#pragma unroll
    for (int i = 0; i < 4; ++i)
#pragma unroll
      for (int j = 0; j < 4; ++j)
        atomicAdd(&S[(size_t)(it * 64 + ti * 4 + i) * N + jt * 64 + tj * 4 + j],
                  acc[i][j] * scale);
  }
}

// Row softmax in place. grid = rows, block 256.
__global__ __launch_bounds__(256) void softmax_kernel(float* __restrict__ Sh, int N) {
  float* row = Sh + (size_t)blockIdx.x * N;
  __shared__ float red[4];
  int tid = threadIdx.x;
  float m = -3.0e38f;
  for (int j = tid; j < N; j += 256) m = fmaxf(m, row[j]);
#pragma unroll
  for (int d = 32; d >= 1; d >>= 1) m = fmaxf(m, __shfl_xor(m, d));
  if ((tid & 63) == 0) red[tid >> 6] = m;
  __syncthreads();
  m = fmaxf(fmaxf(red[0], red[1]), fmaxf(red[2], red[3]));
  __syncthreads();
  float s = 0.f;
  for (int j = tid; j < N; j += 256) { float e = __expf(row[j] - m); row[j] = e; s += e; }
#pragma unroll
  for (int d = 32; d >= 1; d >>= 1) s += __shfl_xor(s, d);
  if ((tid & 63) == 0) red[tid >> 6] = s;
  __syncthreads();
  s = red[0] + red[1] + red[2] + red[3];
  float inv = 1.0f / s;
  for (int j = tid; j < N; j += 256) row[j] *= inv;
}

// V-tile loader for PV: tokens [t0,t0+16) x dims [d0,d0+64) -> T[jj*68 + dd]
template<int PH, int PW>
__device__ __forceinline__ void load_v_tile(const float* __restrict__ base, int d0, int t0,
                                            float* __restrict__ T) {
  const int PP = PH * PW, OW = 64 / PW;
  const int TPR   = (OW < 16) ? OW : 16;    // tokens per po-row in tile
  const int WIDTH = TPR * PW;               // 64 or 32
  const int RPP   = 256 / WIDTH;            // rows per pass
  const int NPO   = 16 / TPR;
  int lw = threadIdx.x % WIDTH, rg = threadIdx.x / WIDTH;
  int cbase = d0 / PP;
  int pbase = t0 / OW, qbase = t0 % OW;
  int qo = lw / PW, x = lw % PW;
#pragma unroll
  for (int rr = 0; rr < 4; ++rr) {
    int r  = rg + RPP * rr;
    int pi = r % NPO; int t1 = r / NPO; int y = t1 % PH; int ci = t1 / PH;
    float v = base[(size_t)(cbase + ci) * NPOS + ((pbase + pi) * PH + y) * 64 + (qbase + qo) * PW + x];
    T[(pi * TPR + qo) * 68 + ci * PP + y * PW + x] = v;
  }
}

// PV for heads 0..2: att[tok][d] = sum_j P[tok][j] V[j][d]; writes bf16 att [b][pos][c].
// grid (4, (N/64) * (D/64))
template<int HEAD, int PH, int PW>
__global__ __launch_bounds__(256) void pv_kernel(const float* __restrict__ ws_,
                                                 const float* __restrict__ Sh,
                                                 unsigned short* __restrict__ attbf) {
  const int OW = 64 / PW, N = (64 / PH) * OW, D = 64 * PH * PW, PP = PH * PW;
  const int NDC = D / 64;
  int b = blockIdx.x;
  int it = blockIdx.y / NDC, dt = blockIdx.y % NDC;
  int d0 = dt * 64, i0 = it * 64;
  const float* vb = ws_ + VOFF + (size_t)b * CPB + (size_t)HEAD * 64 * NPOS;
  const float* P  = Sh + (size_t)b * N * N;
  unsigned short* ab = attbf + (size_t)b * NPOS * 256;
  __shared__ float Ps[16 * 68];  // [jj][i]
  __shared__ float Vs[16 * 68];  // [jj][dd]
  int tid = threadIdx.x, ti = tid >> 4, tj = tid & 15;
  int pj = tid & 15, pib = tid >> 4;
  float acc[4][4] = {};
  for (int j0 = 0; j0 < N; j0 += 16) {
#pragma unroll
    for (int rr = 0; rr < 4; ++rr)
      Ps[pj * 68 + pib + 16 * rr] = P[(size_t)(i0 + pib + 16 * rr) * N + j0 + pj];
    load_v_tile<PH, PW>(vb, d0, j0, Vs);
    __syncthreads();
#pragma unroll
    for (int jj = 0; jj < 16; ++jj) {
      float4 p4 = *(const float4*)&Ps[jj * 68 + ti * 4];
      float4 v4 = *(const float4*)&Vs[jj * 68 + tj * 4];
      const float* pp = &p4.x; const float* vp = &v4.x;
#pragma unroll
      for (int i = 0; i < 4; ++i)
#pragma unroll
        for (int j = 0; j < 4; ++j) acc[i][j] += pp[i] * vp[j];
    }
    __syncthreads();
  }
#pragma unroll
  for (int i = 0; i < 4; ++i) {
    int tok = i0 + ti * 4 + i;
    int po = tok / OW, qo = tok % OW;
#pragma unroll
    for (int j = 0; j < 4; ++j) {
      int d = d0 + tj * 4 + j;
      int c = d / PP, rem = d % PP, y = rem / PW, x = rem % PW;
      int pos = (po * PH + y) * 64 + qo * PW + x;
      ab[(size_t)pos * 256 + HEAD * 64 + c] = f2bf(acc[i][j]);
    }
  }
}

// ---------------------------------------------------------------------------
// Head 3 (1x1 patches): flash attention, n=4096, d=64; writes bf16 att [b][pos][c].
__global__ __launch_bounds__(256) void flash_head3(const float* __restrict__ ws_,
                                                   unsigned short* __restrict__ attbf) {
  int b = blockIdx.x; int q0 = blockIdx.y * 64;
  const float* qb = ws_ + QOFF + (size_t)b * CPB + (size_t)192 * NPOS;
  const float* kb = ws_ + KOFF + (size_t)b * CPB + (size_t)192 * NPOS;
  const float* vb = ws_ + VOFF + (size_t)b * CPB + (size_t)192 * NPOS;
  unsigned short* ab = attbf + (size_t)b * NPOS * 256;
  __shared__ float Qs[64 * 68];  // [ch][pos]
  __shared__ float Ks[64 * 68];  // [ch][pos]; reused as Ps = [kj][qi] after S phase
  __shared__ float Vs[64 * 68];  // [pos][ch] (transposed at load)
  float* Psh = Ks;
  int tid = threadIdx.x, ti = tid >> 4, tj = tid & 15;
  int lp = tid & 63, lg = tid >> 6;
#pragma unroll
  for (int rr = 0; rr < 16; ++rr) {
    int c = lg * 16 + rr;
    Qs[c * 68 + lp] = qb[(size_t)c * NPOS + q0 + lp];
  }
  float mrow[4] = {-3.0e38f, -3.0e38f, -3.0e38f, -3.0e38f};
  float lrow[4] = {0.f, 0.f, 0.f, 0.f};
  float accd[4][4] = {};  // [jd = channel][iq = query]
  for (int kt = 0; kt < 4096; kt += 64) {
    __syncthreads();
#pragma unroll
    for (int rr = 0; rr < 16; ++rr) {
      int c = lg * 16 + rr;
      float kvv = kb[(size_t)c * NPOS + kt + lp];
      float vvv = vb[(size_t)c * NPOS + kt + lp];
      Ks[c * 68 + lp] = kvv;
      Vs[lp * 68 + c] = vvv;
    }
    __syncthreads();
    float s[4][4] = {};
#pragma unroll 8
    for (int c = 0; c < 64; ++c) {
      float4 a4 = *(const float4*)&Qs[c * 68 + ti * 4];
      float4 b4 = *(const float4*)&Ks[c * 68 + tj * 4];
      const float* ap = &a4.x; const float* bp = &b4.x;
#pragma unroll
      for (int i = 0; i < 4; ++i)
#pragma unroll
        for (int j = 0; j < 4; ++j) s[i][j] += ap[i] * bp[j];
    }
#pragma unroll
    for (int i = 0; i < 4; ++i) {
      float tm = fmaxf(fmaxf(s[i][0] * 0.125f, s[i][1] * 0.125f),
                       fmaxf(s[i][2] * 0.125f, s[i][3] * 0.125f));
#pragma unroll
      for (int d = 8; d >= 1; d >>= 1) tm = fmaxf(tm, __shfl_xor(tm, d));
      float mnew = fmaxf(mrow[i], tm);
      float f = __expf(mrow[i] - mnew);
      float rs = 0.f;
#pragma unroll
      for (int j = 0; j < 4; ++j) {
        s[i][j] = __expf(s[i][j] * 0.125f - mnew);
        rs += s[i][j];
      }
#pragma unroll
      for (int d = 8; d >= 1; d >>= 1) rs += __shfl_xor(rs, d);
      lrow[i] = lrow[i] * f + rs;
      mrow[i] = mnew;
#pragma unroll
      for (int jd = 0; jd < 4; ++jd) accd[jd][i] *= f;
    }
    __syncthreads();
#pragma unroll
    for (int i = 0; i < 4; ++i)
#pragma unroll
      for (int j = 0; j < 4; ++j)
        Psh[(tj * 4 + j) * 68 + ti * 4 + i] = s[i][j];
    __syncthreads();
#pragma unroll 8
    for (int jj = 0; jj < 64; ++jj) {
      float4 p4 = *(const float4*)&Psh[jj * 68 + ti * 4];
      float4 v4 = *(const float4*)&Vs[jj * 68 + tj * 4];
      const float* pp = &p4.x; const float* vp = &v4.x;
#pragma unroll
      for (int jd = 0; jd < 4; ++jd)
#pragma unroll
        for (int iq = 0; iq < 4; ++iq) accd[jd][iq] += vp[jd] * pp[iq];
    }
  }
  float inv[4];
#pragma unroll
  for (int i = 0; i < 4; ++i) inv[i] = 1.0f / lrow[i];
#pragma unroll
  for (int iq = 0; iq < 4; ++iq) {
    int q = q0 + ti * 4 + iq;
    ushort4 pk;
    pk.x = f2bf(accd[0][iq] * inv[iq]);
    pk.y = f2bf(accd[1][iq] * inv[iq]);
    pk.z = f2bf(accd[2][iq] * inv[iq]);
    pk.w = f2bf(accd[3][iq] * inv[iq]);
    *(ushort4*)&ab[(size_t)q * 256 + 192 + tj * 4] = pk;
  }
}

// ---------------------------------------------------------------------------
// Wo [o][c][ky][kx] fp32 -> W2 [k=ky*3+kx][o][c] bf16
__global__ __launch_bounds__(256) void transpose_wo_bf(const float* __restrict__ Wo,
                                                       unsigned short* __restrict__ W2) {
  int idx = blockIdx.x * 256 + threadIdx.x;  // 589824 total
  int o = idx / 2304, r = idx % 2304;
  int c = r / 9, k = r % 9;
  W2[(size_t)k * 65536 + (size_t)o * 256 + c] = f2bf(Wo[idx]);
}

// 3x3 SAME conv (bf16 MFMA implicit GEMM) + BN + LeakyReLU(0.2).
// grid (32 h-pairs, 4 o-tiles, 4 b), 256 threads (4 waves).
// Block out-tile: 64 o x 2 h x 64 w. Wave wi: hrow=wi>>1, wseg=wi&1 -> 64o x 32pos, acc[4][2].
__global__ __launch_bounds__(256) void conv_mfma(
    const unsigned short* __restrict__ attbf, const unsigned short* __restrict__ w2,
    const float* __restrict__ bo, const float* __restrict__ gamma,
    const float* __restrict__ beta, const float* __restrict__ rmean,
    const float* __restrict__ rvar, float* __restrict__ out) {
  int hp = blockIdx.x, ot = blockIdx.y, b = blockIdx.z;
  int h0 = hp * 2, o0 = ot * 64;
  // rows padded to 72 bf16 (144B): 16B-aligned b128 frags, ~2-way bank aliasing
  __shared__ unsigned short As[2 * 66 * 72];   // [rowl][w(-1..64)+1][c 0..63]
  __shared__ unsigned short Ws[3 * 64 * 72];   // [dx][o_local][c 0..63]
  int tid = threadIdx.x;
  int wi = tid >> 6, l = tid & 63;
  int hrow = wi >> 1, wseg = wi & 1;
  int lg = l >> 4, ll = l & 15;
  const size_t attb = (size_t)b * NPOS * 256;
  f32x4 acc[4][2];
#pragma unroll
  for (int mi = 0; mi < 4; ++mi)
#pragma unroll
    for (int ni = 0; ni < 2; ++ni) acc[mi][ni] = (f32x4){0.f, 0.f, 0.f, 0.f};

  for (int dy = 0; dy < 3; ++dy) {
    for (int c0 = 0; c0 < 256; c0 += 64) {
      __syncthreads();  // previous compute done before overwrite
      if (tid < 128) {  // stage att rows: rowl 0,1 -> global row h0+dy-1+rowl
        int rowl = tid >> 6, w = tid & 63;
        int ghh = h0 + dy - 1 + rowl;
        uint4 z = make_uint4(0u, 0u, 0u, 0u);
        uint4 a[8];  // 64 bf16 channels = 128 B = 8 x uint4
        if (ghh >= 0 && ghh < 64) {
          const uint4* src = (const uint4*)(attbf + attb + ((size_t)(ghh * 64 + w) * 256 + c0));
#pragma unroll
          for (int q = 0; q < 8; ++q) a[q] = src[q];
        } else {
#pragma unroll
          for (int q = 0; q < 8; ++q) a[q] = z;
        }
        uint4* dst = (uint4*)&As[(rowl * 66 + 1 + w) * 72];
#pragma unroll
        for (int q = 0; q < 8; ++q) dst[q] = a[q];
        if (w == 0 || w == 63) {  // zero the halo columns (w = -1 and w = 64)
          uint4* dz = (uint4*)&As[(rowl * 66 + ((w == 0) ? 0 : 65)) * 72];
#pragma unroll
          for (int q = 0; q < 8; ++q) dz[q] = z;
        }
      }
      if (tid >= 64) {  // stage weights: 3 dx x 64 o rows of 64 c
        int p = tid - 64;
        int dx = p >> 6, ol = p & 63;
        const uint4* src = (const uint4*)(w2 + ((size_t)(dy * 3 + dx) * 65536 +
                                                (size_t)(o0 + ol) * 256 + c0));
        uint4* dst = (uint4*)&Ws[(dx * 64 + ol) * 72];
#pragma unroll
        for (int q = 0; q < 8; ++q) dst[q] = src[q];
      }
      __syncthreads();
#pragma unroll
      for (int dx = 0; dx < 3; ++dx) {
#pragma unroll
        for (int ks = 0; ks < 2; ++ks) {
          bf16x8 af[4];
#pragma unroll
          for (int mi = 0; mi < 4; ++mi)
            af[mi] = *(const bf16x8*)&Ws[(dx * 64 + mi * 16 + ll) * 72 + ks * 32 + lg * 8];
#pragma unroll
          for (int ni = 0; ni < 2; ++ni) {
            bf16x8 bfr = *(const bf16x8*)&As[(hrow * 66 + wseg * 32 + ni * 16 + ll + dx) * 72 +
                                             ks * 32 + lg * 8];
#pragma unroll
            for (int mi = 0; mi < 4; ++mi)
              acc[mi][ni] = __builtin_amdgcn_mfma_f32_16x16x32_bf16(af[mi], bfr, acc[mi][ni],
                                                                    0, 0, 0);
          }
        }
      }
    }
  }
  // epilogue: bias + BN + LeakyReLU, write fp32 out [b][o][h][w]
  int h = h0 + hrow;
#pragma unroll
  for (int mi = 0; mi < 4; ++mi) {
#pragma unroll
    for (int r = 0; r < 4; ++r) {
      int o = o0 + mi * 16 + lg * 4 + r;
      float g  = gamma[o] * rsqrtf(rvar[o] + 1e-5f);
      float bb = (bo[o] - rmean[o]) * g + beta[o];
#pragma unroll
      for (int ni = 0; ni < 2; ++ni) {
        float zv = acc[mi][ni][r] * g + bb;
        zv = (zv >= 0.f) ? zv : 0.2f * zv;
        out[((size_t)(b * 256 + o)) * NPOS + h * 64 + wseg * 32 + ni * 16 + ll] = zv;
      }
    }
  }
}

// ---------------------------------------------------------------------------
extern "C" void kernel_launch(void* const* d_in, const int* in_sizes, int n_in,
                              void* d_out, int out_size, void* d_ws, size_t ws_size,
                              hipStream_t stream) {
  (void)in_sizes; (void)n_in; (void)out_size; (void)ws_size;
  const float* x     = (const float*)d_in[0];
  const float* Wq    = (const float*)d_in[1];
  const float* bq    = (const float*)d_in[2];
  const float* Wk    = (const float*)d_in[3];
  const float* bk    = (const float*)d_in[4];
  const float* Wv    = (const float*)d_in[5];
  const float* bv    = (const float*)d_in[6];
  const float* Wo    = (const float*)d_in[7];
  const float* bo    = (const float*)d_in[8];
  const float* gamma = (const float*)d_in[9];
  const float* beta  = (const float*)d_in[10];
  const float* rmean = (const float*)d_in[11];
  const float* rvar  = (const float*)d_in[12];
  float* ws  = (float*)d_ws;
  float* out = (float*)d_out;
  unsigned short* attbf = (unsigned short*)(ws + AOFF);
  unsigned short* w2bf  = (unsigned short*)(ws + WTOFF);

  hipMemsetAsync(ws + S0OFF, 0, (size_t)4 * 64 * 64 * sizeof(float), stream);
  transpose_wo_bf<<<2304, 256, 0, stream>>>(Wo, w2bf);
  qkv_gemm<<<dim3(64, 4, 12), 256, 0, stream>>>(x, Wq, Wk, Wv, bq, bk, bv, ws);

  score_kernel<0, 8, 8, 8><<<dim3(4, 1, 8),   256, 0, stream>>>(ws, ws + S0OFF);
  score_kernel<1, 4, 4, 1><<<dim3(4, 16, 1),  256, 0, stream>>>(ws, ws + S1OFF);
  score_kernel<2, 2, 2, 1><<<dim3(4, 256, 1), 256, 0, stream>>>(ws, ws + S2OFF);

  softmax_kernel<<<4 * 64,   256, 0, stream>>>(ws + S0OFF, 64);
  softmax_kernel<<<4 * 256,  256, 0, stream>>>(ws + S1OFF, 256);
  softmax_kernel<<<4 * 1024, 256, 0, stream>>>(ws + S2OFF, 1024);

  pv_kernel<0, 8, 8><<<dim3(4, 64), 256, 0, stream>>>(ws, ws + S0OFF, attbf);
  pv_kernel<1, 4, 4><<<dim3(4, 64), 256, 0, stream>>>(ws, ws + S1OFF, attbf);
  pv_kernel<2, 2, 2><<<dim3(4, 64), 256, 0, stream>>>(ws, ws + S2OFF, attbf);
  flash_head3<<<dim3(4, 64), 256, 0, stream>>>(ws, attbf);

  conv_mfma<<<dim3(32, 4, 4), 256, 0, stream>>>(attbf, w2bf, bo, gamma, beta,
                                                rmean, rvar, out);
}

// Round 4
// 558.284 us; speedup vs baseline: 2.0772x; 1.2958x over previous
//
#include <hip/hip_runtime.h>
#include <math.h>

// Problem constants: b=4, C=256, H=W=64
#define NPOS 4096            // 64*64 spatial positions
#define CPB  1048576         // C*NPOS, per-batch stride in q/k/v
// ws layout (float offsets)
#define QOFF  ((size_t)0)
#define KOFF  ((size_t)4194304)
#define VOFF  ((size_t)8388608)
#define AOFF  ((size_t)12582912)                  // bf16 att, [b][pos][c], 4*4096*256 ushort
#define S0OFF ((size_t)16777216)                  // 4*64*64
#define S1OFF (S0OFF + (size_t)4*64*64)           // 4*256*256
#define S2OFF (S1OFF + (size_t)4*256*256)         // 4*1024*1024
#define WTOFF (S2OFF + (size_t)4*1024*1024)       // bf16 W2 [k][o][c], 9*256*256 ushort
// head-3 bf16 token-major q/k live in the S2 region (S2 scores already consumed
// by pv_kernel<2> before prep_qk3 runs; stream order guarantees this).
#define QT3OFF (S2OFF)                            // 4*4096*64 ushort = 524288 floats
#define KT3OFF (S2OFF + (size_t)524288)

typedef __attribute__((ext_vector_type(8))) short bf16x8;
typedef __attribute__((ext_vector_type(4))) float f32x4;

static __device__ __forceinline__ unsigned short f2bf(float f) {
  union { float f; unsigned u; } v; v.f = f;
  unsigned u = v.u;
  return (unsigned short)((u + 0x7FFFu + ((u >> 16) & 1u)) >> 16);
}

// ---------------------------------------------------------------------------
// Kernel 1: fused QKV 1x1-conv projections (fp32 VALU GEMM).
__global__ __launch_bounds__(256) void qkv_gemm(
    const float* __restrict__ x,
    const float* __restrict__ Wq, const float* __restrict__ Wk, const float* __restrict__ Wv,
    const float* __restrict__ bq, const float* __restrict__ bk, const float* __restrict__ bv,
    float* __restrict__ ws) {
  int b = blockIdx.z / 3, t = blockIdx.z % 3;
  const float* W    = (t == 0) ? Wq : (t == 1) ? Wk : Wv;
  const float* bias = (t == 0) ? bq : (t == 1) ? bk : bv;
  float* outp = ws + (size_t)t * 4194304 + (size_t)b * CPB;
  int o0 = blockIdx.y * 64, p0 = blockIdx.x * 64;
  __shared__ float As[16][64];   // [k][m]
  __shared__ float Bs[16][64];   // [k][n]
  int tid = threadIdx.x;
  int ti = tid >> 4, tj = tid & 15;
  int lm = tid & 63, lg = tid >> 6;
  float acc[4][4] = {};
  for (int k0 = 0; k0 < 256; k0 += 16) {
    float4 av = *(const float4*)&W[(size_t)(o0 + lm) * 256 + k0 + lg * 4];
    As[lg * 4 + 0][lm] = av.x; As[lg * 4 + 1][lm] = av.y;
    As[lg * 4 + 2][lm] = av.z; As[lg * 4 + 3][lm] = av.w;
    for (int r = 0; r < 4; ++r)
      Bs[lg * 4 + r][lm] = x[(size_t)b * CPB + (size_t)(k0 + lg * 4 + r) * NPOS + p0 + lm];
    __syncthreads();
#pragma unroll
    for (int kk = 0; kk < 16; ++kk) {
      float4 a4 = *(const float4*)&As[kk][ti * 4];
      float4 b4 = *(const float4*)&Bs[kk][tj * 4];
      const float* ap = &a4.x; const float* bp = &b4.x;
#pragma unroll
      for (int i = 0; i < 4; ++i)
#pragma unroll
        for (int j = 0; j < 4; ++j) acc[i][j] += ap[i] * bp[j];
    }
    __syncthreads();
  }
#pragma unroll
  for (int i = 0; i < 4; ++i) {
    float bi = bias[o0 + ti * 4 + i];
    float4 st = make_float4(acc[i][0] + bi, acc[i][1] + bi, acc[i][2] + bi, acc[i][3] + bi);
    *(float4*)&outp[(size_t)(o0 + ti * 4 + i) * NPOS + p0 + tj * 4] = st;
  }
}

// ---------------------------------------------------------------------------
// Token-tile loader for score kernels: dims [d0,d0+16) x tokens [t0,t0+64) -> T[dc*72 + tl]
template<int PH, int PW>
__device__ __forceinline__ void load_qk_tile(const float* __restrict__ base, int d0, int t0,
                                             float* __restrict__ T) {
  const int PP = PH * PW, OW = 64 / PW;
  const int NPO = 64 / OW;                       // po-rows spanned by 64 tokens
  const int NY  = (PP >= 16) ? (16 / PW) : PH;   // y values in one 16-dim chunk
  int w = threadIdx.x & 63, rg = threadIdx.x >> 6;
  int qo = w / PW, x = w % PW;
  int pbase = t0 / OW;
  int cbase = d0 / PP;
  int ybase = (PP >= 16) ? ((d0 % PP) / PW) : 0;
#pragma unroll
  for (int rr = 0; rr < 4; ++rr) {
    int r  = rg * 4 + rr;                        // 16 rows total
    int pi = r % NPO; int t1 = r / NPO; int yi = t1 % NY; int ci = t1 / NY;
    int c = cbase + ci, y = ybase + yi, po = pbase + pi;
    float v = base[(size_t)c * NPOS + (po * PH + y) * 64 + qo * PW + x];
    T[(ci * PP + yi * PW + x) * 72 + pi * OW + qo] = v;
  }
}

// Scores for heads 0..2: S[b][i][j] = scale * <q_i, k_j>.  grid (4, (N/64)^2, NSLICE)
template<int HEAD, int PH, int PW, int NSLICE>
__global__ __launch_bounds__(256) void score_kernel(const float* __restrict__ ws_,
                                                    float* __restrict__ Sh) {
  const int OW = 64 / PW, OH = 64 / PH, N = OH * OW, D = 64 * PH * PW;
  int b = blockIdx.x;
  const int nt = N / 64;
  int it = blockIdx.y / nt, jt = blockIdx.y % nt;
  const float* qb = ws_ + QOFF + (size_t)b * CPB + (size_t)HEAD * 64 * NPOS;
  const float* kb = ws_ + KOFF + (size_t)b * CPB + (size_t)HEAD * 64 * NPOS;
  float* S = Sh + (size_t)b * N * N;
  __shared__ float Qs[16 * 72], Ks[16 * 72];
  int tid = threadIdx.x, ti = tid >> 4, tj = tid & 15;
  float acc[4][4] = {};
  const int dlen = D / NSLICE;
  int dstart = blockIdx.z * dlen;
  for (int d0 = dstart; d0 < dstart + dlen; d0 += 16) {
    load_qk_tile<PH, PW>(qb, d0, it * 64, Qs);
    load_qk_tile<PH, PW>(kb, d0, jt * 64, Ks);
    __syncthreads();
#pragma unroll
    for (int kk = 0; kk < 16; ++kk) {
      float4 a4 = *(const float4*)&Qs[kk * 72 + ti * 4];
      float4 b4 = *(const float4*)&Ks[kk * 72 + tj * 4];
      const float* ap = &a4.x; const float* bp = &b4.x;
#pragma unroll
      for (int i = 0; i < 4; ++i)
#pragma unroll
        for (int j = 0; j < 4; ++j) acc[i][j] += ap[i] * bp[j];
    }
    __syncthreads();
  }
  float scale = rsqrtf((float)D);
  if (NSLICE == 1) {
#pragma unroll
    for (int i = 0; i < 4; ++i) {
      float4 st = make_float4(acc[i][0] * scale, acc[i][1] * scale,
                              acc[i][2] * scale, acc[i][3] * scale);
      *(float4*)&S[(size_t)(it * 64 + ti * 4 + i) * N + jt * 64 + tj * 4] = st;
    }
  } else {
#pragma unroll
    for (int i = 0; i < 4; ++i)
#pragma unroll
      for (int j = 0; j < 4; ++j)
        atomicAdd(&S[(size_t)(it * 64 + ti * 4 + i) * N + jt * 64 + tj * 4 + j],
                  acc[i][j] * scale);
  }
}

// Row softmax in place. grid = rows, block 256.
__global__ __launch_bounds__(256) void softmax_kernel(float* __restrict__ Sh, int N) {
  float* row = Sh + (size_t)blockIdx.x * N;
  __shared__ float red[4];
  int tid = threadIdx.x;
  float m = -3.0e38f;
  for (int j = tid; j < N; j += 256) m = fmaxf(m, row[j]);
#pragma unroll
  for (int d = 32; d >= 1; d >>= 1) m = fmaxf(m, __shfl_xor(m, d));
  if ((tid & 63) == 0) red[tid >> 6] = m;
  __syncthreads();
  m = fmaxf(fmaxf(red[0], red[1]), fmaxf(red[2], red[3]));
  __syncthreads();
  float s = 0.f;
  for (int j = tid; j < N; j += 256) { float e = __expf(row[j] - m); row[j] = e; s += e; }
#pragma unroll
  for (int d = 32; d >= 1; d >>= 1) s += __shfl_xor(s, d);
  if ((tid & 63) == 0) red[tid >> 6] = s;
  __syncthreads();
  s = red[0] + red[1] + red[2] + red[3];
  float inv = 1.0f / s;
  for (int j = tid; j < N; j += 256) row[j] *= inv;
}

// V-tile loader for PV: tokens [t0,t0+16) x dims [d0,d0+64) -> T[jj*68 + dd]
template<int PH, int PW>
__device__ __forceinline__ void load_v_tile(const float* __restrict__ base, int d0, int t0,
                                            float* __restrict__ T) {
  const int PP = PH * PW, OW = 64 / PW;
  const int TPR   = (OW < 16) ? OW : 16;    // tokens per po-row in tile
  const int WIDTH = TPR * PW;               // 64 or 32
  const int RPP   = 256 / WIDTH;            // rows per pass
  const int NPO   = 16 / TPR;
  int lw = threadIdx.x % WIDTH, rg = threadIdx.x / WIDTH;
  int cbase = d0 / PP;
  int pbase = t0 / OW, qbase = t0 % OW;
  int qo = lw / PW, x = lw % PW;
#pragma unroll
  for (int rr = 0; rr < 4; ++rr) {
    int r  = rg + RPP * rr;
    int pi = r % NPO; int t1 = r / NPO; int y = t1 % PH; int ci = t1 / PH;
    float v = base[(size_t)(cbase + ci) * NPOS + ((pbase + pi) * PH + y) * 64 + (qbase + qo) * PW + x];
    T[(pi * TPR + qo) * 68 + ci * PP + y * PW + x] = v;
  }
}

// PV for heads 0..2: att[tok][d] = sum_j P[tok][j] V[j][d]; writes bf16 att [b][pos][c].
// grid (4, (N/64) * (D/64))
template<int HEAD, int PH, int PW>
__global__ __launch_bounds__(256) void pv_kernel(const float* __restrict__ ws_,
                                                 const float* __restrict__ Sh,
                                                 unsigned short* __restrict__ attbf) {
  const int OW = 64 / PW, N = (64 / PH) * OW, D = 64 * PH * PW, PP = PH * PW;
  const int NDC = D / 64;
  int b = blockIdx.x;
  int it = blockIdx.y / NDC, dt = blockIdx.y % NDC;
  int d0 = dt * 64, i0 = it * 64;
  const float* vb = ws_ + VOFF + (size_t)b * CPB + (size_t)HEAD * 64 * NPOS;
  const float* P  = Sh + (size_t)b * N * N;
  unsigned short* ab = attbf + (size_t)b * NPOS * 256;
  __shared__ float Ps[16 * 68];  // [jj][i]
  __shared__ float Vs[16 * 68];  // [jj][dd]
  int tid = threadIdx.x, ti = tid >> 4, tj = tid & 15;
  int pj = tid & 15, pib = tid >> 4;
  float acc[4][4] = {};
  for (int j0 = 0; j0 < N; j0 += 16) {
#pragma unroll
    for (int rr = 0; rr < 4; ++rr)
      Ps[pj * 68 + pib + 16 * rr] = P[(size_t)(i0 + pib + 16 * rr) * N + j0 + pj];
    load_v_tile<PH, PW>(vb, d0, j0, Vs);
    __syncthreads();
#pragma unroll
    for (int jj = 0; jj < 16; ++jj) {
      float4 p4 = *(const float4*)&Ps[jj * 68 + ti * 4];
      float4 v4 = *(const float4*)&Vs[jj * 68 + tj * 4];
      const float* pp = &p4.x; const float* vp = &v4.x;
#pragma unroll
      for (int i = 0; i < 4; ++i)
#pragma unroll
        for (int j = 0; j < 4; ++j) acc[i][j] += pp[i] * vp[j];
    }
    __syncthreads();
  }
#pragma unroll
  for (int i = 0; i < 4; ++i) {
    int tok = i0 + ti * 4 + i;
    int po = tok / OW, qo = tok % OW;
#pragma unroll
    for (int j = 0; j < 4; ++j) {
      int d = d0 + tj * 4 + j;
      int c = d / PP, rem = d % PP, y = rem / PW, x = rem % PW;
      int pos = (po * PH + y) * 64 + qo * PW + x;
      ab[(size_t)pos * 256 + HEAD * 64 + c] = f2bf(acc[i][j]);
    }
  }
}

// ---------------------------------------------------------------------------
// Head-3 prep: q/k fp32 [ch][pos] -> bf16 token-major [pos][64ch].
// grid (64 pos-tiles, 4 b, 2 tensors), 256 threads. LDS 64x65 transpose tile.
__global__ __launch_bounds__(256) void prep_qk3(const float* __restrict__ ws_,
                                                unsigned short* __restrict__ qt,
                                                unsigned short* __restrict__ kt_) {
  int pt = blockIdx.x, b = blockIdx.y, t = blockIdx.z;
  const float* src = ws_ + (t ? KOFF : QOFF) + (size_t)b * CPB + (size_t)192 * NPOS + pt * 64;
  unsigned short* dst = (t ? kt_ : qt) + (size_t)b * 262144 + (size_t)pt * 64 * 64;
  __shared__ float tile[64][65];
  int tid = threadIdx.x;
  int a = tid >> 6, pz = tid & 63;
#pragma unroll
  for (int r = 0; r < 16; ++r) {
    int ch = a + r * 4;
    tile[pz][ch] = src[(size_t)ch * NPOS + pz];
  }
  __syncthreads();
  int ch2 = tid & 63, pr = tid >> 6;
#pragma unroll
  for (int r = 0; r < 16; ++r) {
    int pos = pr + r * 4;
    dst[(size_t)pos * 64 + ch2] = f2bf(tile[pos][ch2]);
  }
}

// Head 3: bf16 MFMA flash attention. n=4096, d=64. grid (4 b, 64 q-tiles), 4 waves.
// Wave wv owns 16 queries. Fragment algebra identical to conv_mfma (HW-verified):
// A-frag row=l&15, k=(l>>4)*8; D: col=l&15, row=(l>>4)*4+reg.
__global__ __launch_bounds__(256) void flash3_mfma(const float* __restrict__ ws_,
                                                   const unsigned short* __restrict__ qt,
                                                   const unsigned short* __restrict__ kt_,
                                                   unsigned short* __restrict__ attbf) {
  int b = blockIdx.x; int q0 = blockIdx.y * 64;
  const unsigned short* Q = qt + (size_t)b * 262144;
  const unsigned short* K = kt_ + (size_t)b * 262144;
  const float* Vg = ws_ + VOFF + (size_t)b * CPB + (size_t)192 * NPOS;  // [64ch][4096]
  unsigned short* ab = attbf + (size_t)b * NPOS * 256;

  __shared__ unsigned short Ks[64 * 72];     // [key][ch], row pad 72
  __shared__ unsigned short Vs[64 * 72];     // [ch][key]  (native from [ch][pos])
  __shared__ unsigned short Ps[4][16 * 72];  // per-wave P [q][key]

  int tid = threadIdx.x;
  int wv = tid >> 6, l = tid & 63;
  int lg = l >> 4, ll = l & 15;
  int qw = q0 + wv * 16;

  // Q fragments held in registers for the whole kernel
  bf16x8 qf[2];
  qf[0] = *(const bf16x8*)&Q[(size_t)(qw + ll) * 64 + lg * 8];
  qf[1] = *(const bf16x8*)&Q[(size_t)(qw + ll) * 64 + 32 + lg * 8];

  float m_r[4] = {-3.0e38f, -3.0e38f, -3.0e38f, -3.0e38f};
  float l_r[4] = {0.f, 0.f, 0.f, 0.f};
  f32x4 o_acc[4];
#pragma unroll
  for (int c = 0; c < 4; ++c) o_acc[c] = (f32x4){0.f, 0.f, 0.f, 0.f};

  int skey = tid >> 3, spart = tid & 7;      // K staging: 32 keys/pass, 8x16B per key row
  int vch = tid >> 2, vkq = (tid & 3) * 16;  // V staging: ch x 16-key strip

  for (int kt0 = 0; kt0 < 4096; kt0 += 64) {
    __syncthreads();  // all waves done reading Ks/Vs of previous tile
#pragma unroll
    for (int ps = 0; ps < 2; ++ps) {
      int kk = ps * 32 + skey;
      *(uint4*)&Ks[kk * 72 + spart * 8] =
          *(const uint4*)&K[(size_t)(kt0 + kk) * 64 + spart * 8];
    }
#pragma unroll
    for (int u = 0; u < 4; ++u) {
      float4 v4 = *(const float4*)&Vg[(size_t)vch * NPOS + kt0 + vkq + u * 4];
      ushort4 pk;
      pk.x = f2bf(v4.x); pk.y = f2bf(v4.y); pk.z = f2bf(v4.z); pk.w = f2bf(v4.w);
      *(ushort4*)&Vs[vch * 72 + vkq + u * 4] = pk;
    }
    __syncthreads();
    // S = Q K^T : 16q x 64 keys per wave
    f32x4 s_acc[4];
#pragma unroll
    for (int n = 0; n < 4; ++n) s_acc[n] = (f32x4){0.f, 0.f, 0.f, 0.f};
#pragma unroll
    for (int n = 0; n < 4; ++n)
#pragma unroll
      for (int ks = 0; ks < 2; ++ks) {
        bf16x8 kf = *(const bf16x8*)&Ks[(n * 16 + ll) * 72 + ks * 32 + lg * 8];
        s_acc[n] = __builtin_amdgcn_mfma_f32_16x16x32_bf16(qf[ks], kf, s_acc[n], 0, 0, 0);
      }
    // online softmax; row q = qw + lg*4 + r lives in the 16 lanes sharing lg
    float f_r[4];
#pragma unroll
    for (int r = 0; r < 4; ++r) {
      float mx = fmaxf(fmaxf(s_acc[0][r], s_acc[1][r]),
                       fmaxf(s_acc[2][r], s_acc[3][r])) * 0.125f;
#pragma unroll
      for (int d = 8; d >= 1; d >>= 1) mx = fmaxf(mx, __shfl_xor(mx, d));
      float mn = fmaxf(m_r[r], mx);
      f_r[r] = __expf(m_r[r] - mn);
      m_r[r] = mn;
      float rs = 0.f;
#pragma unroll
      for (int n = 0; n < 4; ++n) {
        float p = __expf(s_acc[n][r] * 0.125f - mn);
        s_acc[n][r] = p;
        rs += p;
      }
#pragma unroll
      for (int d = 8; d >= 1; d >>= 1) rs += __shfl_xor(rs, d);
      l_r[r] = l_r[r] * f_r[r] + rs;
#pragma unroll
      for (int c = 0; c < 4; ++c) o_acc[c][r] *= f_r[r];
    }
    // P -> per-wave LDS tile (same-wave write->read; compiler inserts lgkmcnt)
#pragma unroll
    for (int r = 0; r < 4; ++r)
#pragma unroll
      for (int n = 0; n < 4; ++n)
        Ps[wv][(lg * 4 + r) * 72 + n * 16 + ll] = f2bf(s_acc[n][r]);
    // O += P V : A = P [16q x 64key], B = V [64key x 64ch]
#pragma unroll
    for (int ks = 0; ks < 2; ++ks) {
      bf16x8 pa = *(const bf16x8*)&Ps[wv][ll * 72 + ks * 32 + lg * 8];
#pragma unroll
      for (int c = 0; c < 4; ++c) {
        bf16x8 vf = *(const bf16x8*)&Vs[(c * 16 + ll) * 72 + ks * 32 + lg * 8];
        o_acc[c] = __builtin_amdgcn_mfma_f32_16x16x32_bf16(pa, vf, o_acc[c], 0, 0, 0);
      }
    }
  }
#pragma unroll
  for (int r = 0; r < 4; ++r) {
    float inv = 1.0f / l_r[r];
    int q = qw + lg * 4 + r;
#pragma unroll
    for (int c = 0; c < 4; ++c)
      ab[(size_t)q * 256 + 192 + c * 16 + ll] = f2bf(o_acc[c][r] * inv);
  }
}

// ---------------------------------------------------------------------------
// Wo [o][c][ky][kx] fp32 -> W2 [k=ky*3+kx][o][c] bf16
__global__ __launch_bounds__(256) void transpose_wo_bf(const float* __restrict__ Wo,
                                                       unsigned short* __restrict__ W2) {
  int idx = blockIdx.x * 256 + threadIdx.x;  // 589824 total
  int o = idx / 2304, r = idx % 2304;
  int c = r / 9, k = r % 9;
  W2[(size_t)k * 65536 + (size_t)o * 256 + c] = f2bf(Wo[idx]);
}

// 3x3 SAME conv (bf16 MFMA implicit GEMM) + BN + LeakyReLU(0.2).
// grid (32 h-pairs, 4 o-tiles, 4 b), 256 threads (4 waves).
__global__ __launch_bounds__(256) void conv_mfma(
    const unsigned short* __restrict__ attbf, const unsigned short* __restrict__ w2,
    const float* __restrict__ bo, const float* __restrict__ gamma,
    const float* __restrict__ beta, const float* __restrict__ rmean,
    const float* __restrict__ rvar, float* __restrict__ out) {
  int hp = blockIdx.x, ot = blockIdx.y, b = blockIdx.z;
  int h0 = hp * 2, o0 = ot * 64;
  __shared__ unsigned short As[2 * 66 * 72];   // [rowl][w(-1..64)+1][c 0..63]
  __shared__ unsigned short Ws[3 * 64 * 72];   // [dx][o_local][c 0..63]
  int tid = threadIdx.x;
  int wi = tid >> 6, l = tid & 63;
  int hrow = wi >> 1, wseg = wi & 1;
  int lg = l >> 4, ll = l & 15;
  const size_t attb = (size_t)b * NPOS * 256;
  f32x4 acc[4][2];
#pragma unroll
  for (int mi = 0; mi < 4; ++mi)
#pragma unroll
    for (int ni = 0; ni < 2; ++ni) acc[mi][ni] = (f32x4){0.f, 0.f, 0.f, 0.f};

  for (int dy = 0; dy < 3; ++dy) {
    for (int c0 = 0; c0 < 256; c0 += 64) {
      __syncthreads();
      if (tid < 128) {
        int rowl = tid >> 6, w = tid & 63;
        int ghh = h0 + dy - 1 + rowl;
        uint4 z = make_uint4(0u, 0u, 0u, 0u);
        uint4 a[8];
        if (ghh >= 0 && ghh < 64) {
          const uint4* src = (const uint4*)(attbf + attb + ((size_t)(ghh * 64 + w) * 256 + c0));
#pragma unroll
          for (int q = 0; q < 8; ++q) a[q] = src[q];
        } else {
#pragma unroll
          for (int q = 0; q < 8; ++q) a[q] = z;
        }
        uint4* dst = (uint4*)&As[(rowl * 66 + 1 + w) * 72];
#pragma unroll
        for (int q = 0; q < 8; ++q) dst[q] = a[q];
        if (w == 0 || w == 63) {
          uint4* dz = (uint4*)&As[(rowl * 66 + ((w == 0) ? 0 : 65)) * 72];
#pragma unroll
          for (int q = 0; q < 8; ++q) dz[q] = z;
        }
      }
      if (tid >= 64) {
        int p = tid - 64;
        int dx = p >> 6, ol = p & 63;
        const uint4* src = (const uint4*)(w2 + ((size_t)(dy * 3 + dx) * 65536 +
                                                (size_t)(o0 + ol) * 256 + c0));
        uint4* dst = (uint4*)&Ws[(dx * 64 + ol) * 72];
#pragma unroll
        for (int q = 0; q < 8; ++q) dst[q] = src[q];
      }
      __syncthreads();
#pragma unroll
      for (int dx = 0; dx < 3; ++dx) {
#pragma unroll
        for (int ks = 0; ks < 2; ++ks) {
          bf16x8 af[4];
#pragma unroll
          for (int mi = 0; mi < 4; ++mi)
            af[mi] = *(const bf16x8*)&Ws[(dx * 64 + mi * 16 + ll) * 72 + ks * 32 + lg * 8];
#pragma unroll
          for (int ni = 0; ni < 2; ++ni) {
            bf16x8 bfr = *(const bf16x8*)&As[(hrow * 66 + wseg * 32 + ni * 16 + ll + dx) * 72 +
                                             ks * 32 + lg * 8];
#pragma unroll
            for (int mi = 0; mi < 4; ++mi)
              acc[mi][ni] = __builtin_amdgcn_mfma_f32_16x16x32_bf16(af[mi], bfr, acc[mi][ni],
                                                                    0, 0, 0);
          }
        }
      }
    }
  }
  int h = h0 + hrow;
#pragma unroll
  for (int mi = 0; mi < 4; ++mi) {
#pragma unroll
    for (int r = 0; r < 4; ++r) {
      int o = o0 + mi * 16 + lg * 4 + r;
      float g  = gamma[o] * rsqrtf(rvar[o] + 1e-5f);
      float bb = (bo[o] - rmean[o]) * g + beta[o];
#pragma unroll
      for (int ni = 0; ni < 2; ++ni) {
        float zv = acc[mi][ni][r] * g + bb;
        zv = (zv >= 0.f) ? zv : 0.2f * zv;
        out[((size_t)(b * 256 + o)) * NPOS + h * 64 + wseg * 32 + ni * 16 + ll] = zv;
      }
    }
  }
}

// ---------------------------------------------------------------------------
extern "C" void kernel_launch(void* const* d_in, const int* in_sizes, int n_in,
                              void* d_out, int out_size, void* d_ws, size_t ws_size,
                              hipStream_t stream) {
  (void)in_sizes; (void)n_in; (void)out_size; (void)ws_size;
  const float* x     = (const float*)d_in[0];
  const float* Wq    = (const float*)d_in[1];
  const float* bq    = (const float*)d_in[2];
  const float* Wk    = (const float*)d_in[3];
  const float* bk    = (const float*)d_in[4];
  const float* Wv    = (const float*)d_in[5];
  const float* bv    = (const float*)d_in[6];
  const float* Wo    = (const float*)d_in[7];
  const float* bo    = (const float*)d_in[8];
  const float* gamma = (const float*)d_in[9];
  const float* beta  = (const float*)d_in[10];
  const float* rmean = (const float*)d_in[11];
  const float* rvar  = (const float*)d_in[12];
  float* ws  = (float*)d_ws;
  float* out = (float*)d_out;
  unsigned short* attbf = (unsigned short*)(ws + AOFF);
  unsigned short* w2bf  = (unsigned short*)(ws + WTOFF);
  unsigned short* qt3   = (unsigned short*)(ws + QT3OFF);
  unsigned short* kt3   = (unsigned short*)(ws + KT3OFF);

  hipMemsetAsync(ws + S0OFF, 0, (size_t)4 * 64 * 64 * sizeof(float), stream);
  transpose_wo_bf<<<2304, 256, 0, stream>>>(Wo, w2bf);
  qkv_gemm<<<dim3(64, 4, 12), 256, 0, stream>>>(x, Wq, Wk, Wv, bq, bk, bv, ws);

  score_kernel<0, 8, 8, 8><<<dim3(4, 1, 8),   256, 0, stream>>>(ws, ws + S0OFF);
  score_kernel<1, 4, 4, 1><<<dim3(4, 16, 1),  256, 0, stream>>>(ws, ws + S1OFF);
  score_kernel<2, 2, 2, 1><<<dim3(4, 256, 1), 256, 0, stream>>>(ws, ws + S2OFF);

  softmax_kernel<<<4 * 64,   256, 0, stream>>>(ws + S0OFF, 64);
  softmax_kernel<<<4 * 256,  256, 0, stream>>>(ws + S1OFF, 256);
  softmax_kernel<<<4 * 1024, 256, 0, stream>>>(ws + S2OFF, 1024);

  pv_kernel<0, 8, 8><<<dim3(4, 64), 256, 0, stream>>>(ws, ws + S0OFF, attbf);
  pv_kernel<1, 4, 4><<<dim3(4, 64), 256, 0, stream>>>(ws, ws + S1OFF, attbf);
  pv_kernel<2, 2, 2><<<dim3(4, 64), 256, 0, stream>>>(ws, ws + S2OFF, attbf);

  // head 3: prep reuses the S2 region (its scores are consumed by pv_kernel<2> above)
  prep_qk3<<<dim3(64, 4, 2), 256, 0, stream>>>(ws, qt3, kt3);
  flash3_mfma<<<dim3(4, 64), 256, 0, stream>>>(ws, qt3, kt3, attbf);

  conv_mfma<<<dim3(32, 4, 4), 256, 0, stream>>>(attbf, w2bf, bo, gamma, beta,
                                                rmean, rvar, out);
}

// Round 5
// 403.591 us; speedup vs baseline: 2.8734x; 1.3833x over previous
//
#include <hip/hip_runtime.h>
#include <math.h>

// Problem constants: b=4, C=256, H=W=64
#define NPOS 4096            // 64*64 spatial positions
#define CPB  1048576         // C*NPOS, per-batch stride in q/k/v
// ws layout (float offsets)
#define QOFF  ((size_t)0)
#define KOFF  ((size_t)4194304)
#define VOFF  ((size_t)8388608)
#define AOFF  ((size_t)12582912)                  // bf16 att, [b][pos][c], 4*4096*256 ushort
#define S0OFF ((size_t)16777216)                  // 4*64*64
#define S1OFF (S0OFF + (size_t)4*64*64)           // 4*256*256
#define S2OFF (S1OFF + (size_t)4*256*256)         // 4*1024*1024
#define WTOFF (S2OFF + (size_t)4*1024*1024)       // bf16 W2 [k][o][c], 9*256*256 ushort
// head-3 scratch inside the (already-consumed) S2 region:
#define QT3OFF (S2OFF)                            // 4*4096*64 ushort = 524288 floats
#define KT3OFF (S2OFF + (size_t)524288)           // same size
#define MLOFF  (S2OFF + (size_t)1048576)          // (m,l) per (b,split,q): 4*4*4096*2 floats
// split-KV partial O reuses the dead Q fp32 region: 4*4*4096*64 = 4194304 floats exactly
#define OPOFF QOFF

typedef __attribute__((ext_vector_type(8))) short bf16x8;
typedef __attribute__((ext_vector_type(4))) float f32x4;

static __device__ __forceinline__ unsigned short f2bf(float f) {
  union { float f; unsigned u; } v; v.f = f;
  unsigned u = v.u;
  return (unsigned short)((u + 0x7FFFu + ((u >> 16) & 1u)) >> 16);
}

// ---------------------------------------------------------------------------
// QKV 1x1-conv projections via bf16 MFMA, fp32 out (interfaces unchanged).
// grid (64 p-tiles, 4 o-tiles, 12 = b*3+t), 256 threads (4 waves).
// Wave wv owns 64o x 16p. Fragment algebra as conv_mfma (HW-verified):
// D col = l&15 -> p, row = (l>>4)*4+reg -> o.
__global__ __launch_bounds__(256) void qkv_mfma(
    const float* __restrict__ x,
    const float* __restrict__ Wq, const float* __restrict__ Wk, const float* __restrict__ Wv,
    const float* __restrict__ bq, const float* __restrict__ bk, const float* __restrict__ bv,
    float* __restrict__ ws) {
  int b = blockIdx.z / 3, t = blockIdx.z % 3;
  const float* W    = (t == 0) ? Wq : (t == 1) ? Wk : Wv;
  const float* bias = (t == 0) ? bq : (t == 1) ? bk : bv;
  float* outp = ws + (size_t)t * 4194304 + (size_t)b * CPB;
  int o0 = blockIdx.y * 64, p0 = blockIdx.x * 64;
  __shared__ unsigned short Wt[64 * 72];  // [o_local][c 0..63]
  __shared__ unsigned short Xs[64 * 72];  // [p_local][c 0..63] (transposed at load)
  int tid = threadIdx.x;
  int wv = tid >> 6, l = tid & 63;
  int lg = l >> 4, ll = l & 15;
  f32x4 acc[4];
#pragma unroll
  for (int mi = 0; mi < 4; ++mi) acc[mi] = (f32x4){0.f, 0.f, 0.f, 0.f};

  int wol = tid >> 2, wcp = (tid & 3) * 16;  // W staging: 64 rows x (4 lanes x 16c)
  int xcc = tid >> 6, xpz = tid & 63;        // X staging: coalesced in p, transpose to [p][c]

  for (int c0 = 0; c0 < 256; c0 += 64) {
    __syncthreads();
#pragma unroll
    for (int u = 0; u < 4; ++u) {
      float4 w4 = *(const float4*)&W[(size_t)(o0 + wol) * 256 + c0 + wcp + u * 4];
      ushort4 pk;
      pk.x = f2bf(w4.x); pk.y = f2bf(w4.y); pk.z = f2bf(w4.z); pk.w = f2bf(w4.w);
      *(ushort4*)&Wt[wol * 72 + wcp + u * 4] = pk;
    }
#pragma unroll
    for (int r = 0; r < 16; ++r) {
      int c = xcc * 16 + r;
      Xs[xpz * 72 + c] = f2bf(x[(size_t)b * CPB + (size_t)(c0 + c) * NPOS + p0 + xpz]);
    }
    __syncthreads();
#pragma unroll
    for (int ks = 0; ks < 2; ++ks) {
      bf16x8 xb = *(const bf16x8*)&Xs[(wv * 16 + ll) * 72 + ks * 32 + lg * 8];
#pragma unroll
      for (int mi = 0; mi < 4; ++mi) {
        bf16x8 wa = *(const bf16x8*)&Wt[(mi * 16 + ll) * 72 + ks * 32 + lg * 8];
        acc[mi] = __builtin_amdgcn_mfma_f32_16x16x32_bf16(wa, xb, acc[mi], 0, 0, 0);
      }
    }
  }
#pragma unroll
  for (int mi = 0; mi < 4; ++mi)
#pragma unroll
    for (int r = 0; r < 4; ++r) {
      int o = o0 + mi * 16 + lg * 4 + r;
      outp[(size_t)o * NPOS + p0 + wv * 16 + ll] = acc[mi][r] + bias[o];
    }
}

// ---------------------------------------------------------------------------
// Token-tile loader for score kernels: dims [d0,d0+16) x tokens [t0,t0+64) -> T[dc*72 + tl]
template<int PH, int PW>
__device__ __forceinline__ void load_qk_tile(const float* __restrict__ base, int d0, int t0,
                                             float* __restrict__ T) {
  const int PP = PH * PW, OW = 64 / PW;
  const int NPO = 64 / OW;                       // po-rows spanned by 64 tokens
  const int NY  = (PP >= 16) ? (16 / PW) : PH;   // y values in one 16-dim chunk
  int w = threadIdx.x & 63, rg = threadIdx.x >> 6;
  int qo = w / PW, x = w % PW;
  int pbase = t0 / OW;
  int cbase = d0 / PP;
  int ybase = (PP >= 16) ? ((d0 % PP) / PW) : 0;
#pragma unroll
  for (int rr = 0; rr < 4; ++rr) {
    int r  = rg * 4 + rr;                        // 16 rows total
    int pi = r % NPO; int t1 = r / NPO; int yi = t1 % NY; int ci = t1 / NY;
    int c = cbase + ci, y = ybase + yi, po = pbase + pi;
    float v = base[(size_t)c * NPOS + (po * PH + y) * 64 + qo * PW + x];
    T[(ci * PP + yi * PW + x) * 72 + pi * OW + qo] = v;
  }
}

// Scores for heads 0..2: S[b][i][j] = scale * <q_i, k_j>.  grid (4, (N/64)^2, NSLICE)
template<int HEAD, int PH, int PW, int NSLICE>
__global__ __launch_bounds__(256) void score_kernel(const float* __restrict__ ws_,
                                                    float* __restrict__ Sh) {
  const int OW = 64 / PW, OH = 64 / PH, N = OH * OW, D = 64 * PH * PW;
  int b = blockIdx.x;
  const int nt = N / 64;
  int it = blockIdx.y / nt, jt = blockIdx.y % nt;
  const float* qb = ws_ + QOFF + (size_t)b * CPB + (size_t)HEAD * 64 * NPOS;
  const float* kb = ws_ + KOFF + (size_t)b * CPB + (size_t)HEAD * 64 * NPOS;
  float* S = Sh + (size_t)b * N * N;
  __shared__ float Qs[16 * 72], Ks[16 * 72];
  int tid = threadIdx.x, ti = tid >> 4, tj = tid & 15;
  float acc[4][4] = {};
  const int dlen = D / NSLICE;
  int dstart = blockIdx.z * dlen;
  for (int d0 = dstart; d0 < dstart + dlen; d0 += 16) {
    load_qk_tile<PH, PW>(qb, d0, it * 64, Qs);
    load_qk_tile<PH, PW>(kb, d0, jt * 64, Ks);
    __syncthreads();
#pragma unroll
    for (int kk = 0; kk < 16; ++kk) {
      float4 a4 = *(const float4*)&Qs[kk * 72 + ti * 4];
      float4 b4 = *(const float4*)&Ks[kk * 72 + tj * 4];
      const float* ap = &a4.x; const float* bp = &b4.x;
#pragma unroll
      for (int i = 0; i < 4; ++i)
#pragma unroll
        for (int j = 0; j < 4; ++j) acc[i][j] += ap[i] * bp[j];
    }
    __syncthreads();
  }
  float scale = rsqrtf((float)D);
  if (NSLICE == 1) {
#pragma unroll
    for (int i = 0; i < 4; ++i) {
      float4 st = make_float4(acc[i][0] * scale, acc[i][1] * scale,
                              acc[i][2] * scale, acc[i][3] * scale);
      *(float4*)&S[(size_t)(it * 64 + ti * 4 + i) * N + jt * 64 + tj * 4] = st;
    }
  } else {
#pragma unroll
    for (int i = 0; i < 4; ++i)
#pragma unroll
      for (int j = 0; j < 4; ++j)
        atomicAdd(&S[(size_t)(it * 64 + ti * 4 + i) * N + jt * 64 + tj * 4 + j],
                  acc[i][j] * scale);
  }
}

// Row softmax in place. grid = rows, block 256.
__global__ __launch_bounds__(256) void softmax_kernel(float* __restrict__ Sh, int N) {
  float* row = Sh + (size_t)blockIdx.x * N;
  __shared__ float red[4];
  int tid = threadIdx.x;
  float m = -3.0e38f;
  for (int j = tid; j < N; j += 256) m = fmaxf(m, row[j]);
#pragma unroll
  for (int d = 32; d >= 1; d >>= 1) m = fmaxf(m, __shfl_xor(m, d));
  if ((tid & 63) == 0) red[tid >> 6] = m;
  __syncthreads();
  m = fmaxf(fmaxf(red[0], red[1]), fmaxf(red[2], red[3]));
  __syncthreads();
  float s = 0.f;
  for (int j = tid; j < N; j += 256) { float e = __expf(row[j] - m); row[j] = e; s += e; }
#pragma unroll
  for (int d = 32; d >= 1; d >>= 1) s += __shfl_xor(s, d);
  if ((tid & 63) == 0) red[tid >> 6] = s;
  __syncthreads();
  s = red[0] + red[1] + red[2] + red[3];
  float inv = 1.0f / s;
  for (int j = tid; j < N; j += 256) row[j] *= inv;
}

// V-tile loader for PV: tokens [t0,t0+16) x dims [d0,d0+64) -> T[jj*68 + dd]
template<int PH, int PW>
__device__ __forceinline__ void load_v_tile(const float* __restrict__ base, int d0, int t0,
                                            float* __restrict__ T) {
  const int PP = PH * PW, OW = 64 / PW;
  const int TPR   = (OW < 16) ? OW : 16;    // tokens per po-row in tile
  const int WIDTH = TPR * PW;               // 64 or 32
  const int RPP   = 256 / WIDTH;            // rows per pass
  const int NPO   = 16 / TPR;
  int lw = threadIdx.x % WIDTH, rg = threadIdx.x / WIDTH;
  int cbase = d0 / PP;
  int pbase = t0 / OW, qbase = t0 % OW;
  int qo = lw / PW, x = lw % PW;
#pragma unroll
  for (int rr = 0; rr < 4; ++rr) {
    int r  = rg + RPP * rr;
    int pi = r % NPO; int t1 = r / NPO; int y = t1 % PH; int ci = t1 / PH;
    float v = base[(size_t)(cbase + ci) * NPOS + ((pbase + pi) * PH + y) * 64 + (qbase + qo) * PW + x];
    T[(pi * TPR + qo) * 68 + ci * PP + y * PW + x] = v;
  }
}

// PV for heads 0..2: att[tok][d] = sum_j P[tok][j] V[j][d]; writes bf16 att [b][pos][c].
// grid (4, (N/64) * (D/64))
template<int HEAD, int PH, int PW>
__global__ __launch_bounds__(256) void pv_kernel(const float* __restrict__ ws_,
                                                 const float* __restrict__ Sh,
                                                 unsigned short* __restrict__ attbf) {
  const int OW = 64 / PW, N = (64 / PH) * OW, D = 64 * PH * PW, PP = PH * PW;
  const int NDC = D / 64;
  int b = blockIdx.x;
  int it = blockIdx.y / NDC, dt = blockIdx.y % NDC;
  int d0 = dt * 64, i0 = it * 64;
  const float* vb = ws_ + VOFF + (size_t)b * CPB + (size_t)HEAD * 64 * NPOS;
  const float* P  = Sh + (size_t)b * N * N;
  unsigned short* ab = attbf + (size_t)b * NPOS * 256;
  __shared__ float Ps[16 * 68];  // [jj][i]
  __shared__ float Vs[16 * 68];  // [jj][dd]
  int tid = threadIdx.x, ti = tid >> 4, tj = tid & 15;
  int pj = tid & 15, pib = tid >> 4;
  float acc[4][4] = {};
  for (int j0 = 0; j0 < N; j0 += 16) {
#pragma unroll
    for (int rr = 0; rr < 4; ++rr)
      Ps[pj * 68 + pib + 16 * rr] = P[(size_t)(i0 + pib + 16 * rr) * N + j0 + pj];
    load_v_tile<PH, PW>(vb, d0, j0, Vs);
    __syncthreads();
#pragma unroll
    for (int jj = 0; jj < 16; ++jj) {
      float4 p4 = *(const float4*)&Ps[jj * 68 + ti * 4];
      float4 v4 = *(const float4*)&Vs[jj * 68 + tj * 4];
      const float* pp = &p4.x; const float* vp = &v4.x;
#pragma unroll
      for (int i = 0; i < 4; ++i)
#pragma unroll
        for (int j = 0; j < 4; ++j) acc[i][j] += pp[i] * vp[j];
    }
    __syncthreads();
  }
#pragma unroll
  for (int i = 0; i < 4; ++i) {
    int tok = i0 + ti * 4 + i;
    int po = tok / OW, qo = tok % OW;
#pragma unroll
    for (int j = 0; j < 4; ++j) {
      int d = d0 + tj * 4 + j;
      int c = d / PP, rem = d % PP, y = rem / PW, x = rem % PW;
      int pos = (po * PH + y) * 64 + qo * PW + x;
      ab[(size_t)pos * 256 + HEAD * 64 + c] = f2bf(acc[i][j]);
    }
  }
}

// ---------------------------------------------------------------------------
// Head-3 prep: q/k fp32 [ch][pos] -> bf16 token-major [pos][64ch].
// grid (64 pos-tiles, 4 b, 2 tensors), 256 threads. LDS 64x65 transpose tile.
__global__ __launch_bounds__(256) void prep_qk3(const float* __restrict__ ws_,
                                                unsigned short* __restrict__ qt,
                                                unsigned short* __restrict__ kt_) {
  int pt = blockIdx.x, b = blockIdx.y, t = blockIdx.z;
  const float* src = ws_ + (t ? KOFF : QOFF) + (size_t)b * CPB + (size_t)192 * NPOS + pt * 64;
  unsigned short* dst = (t ? kt_ : qt) + (size_t)b * 262144 + (size_t)pt * 64 * 64;
  __shared__ float tile[64][65];
  int tid = threadIdx.x;
  int a = tid >> 6, pz = tid & 63;
#pragma unroll
  for (int r = 0; r < 16; ++r) {
    int ch = a + r * 4;
    tile[pz][ch] = src[(size_t)ch * NPOS + pz];
  }
  __syncthreads();
  int ch2 = tid & 63, pr = tid >> 6;
#pragma unroll
  for (int r = 0; r < 16; ++r) {
    int pos = pr + r * 4;
    dst[(size_t)pos * 64 + ch2] = f2bf(tile[pos][ch2]);
  }
}

// Head 3 split-KV flash: grid (4 b, 64 q-tiles, 4 splits), 4 waves.
// Writes unnormalized O partials (fp32) + per-row (m,l).
__global__ __launch_bounds__(256) void flash3_split(const float* __restrict__ ws_,
                                                    const unsigned short* __restrict__ qt,
                                                    const unsigned short* __restrict__ kt_,
                                                    float* __restrict__ opart,
                                                    float* __restrict__ ml) {
  int b = blockIdx.x; int q0 = blockIdx.y * 64; int split = blockIdx.z;
  const unsigned short* Q = qt + (size_t)b * 262144;
  const unsigned short* K = kt_ + (size_t)b * 262144;
  const float* Vg = ws_ + VOFF + (size_t)b * CPB + (size_t)192 * NPOS;  // [64ch][4096]

  __shared__ unsigned short Ks[64 * 72];     // [key][ch], row pad 72
  __shared__ unsigned short Vs[64 * 72];     // [ch][key]  (native from [ch][pos])
  __shared__ unsigned short Ps[4][16 * 72];  // per-wave P [q][key]

  int tid = threadIdx.x;
  int wv = tid >> 6, l = tid & 63;
  int lg = l >> 4, ll = l & 15;
  int qw = q0 + wv * 16;

  bf16x8 qf[2];
  qf[0] = *(const bf16x8*)&Q[(size_t)(qw + ll) * 64 + lg * 8];
  qf[1] = *(const bf16x8*)&Q[(size_t)(qw + ll) * 64 + 32 + lg * 8];

  float m_r[4] = {-3.0e38f, -3.0e38f, -3.0e38f, -3.0e38f};
  float l_r[4] = {0.f, 0.f, 0.f, 0.f};
  f32x4 o_acc[4];
#pragma unroll
  for (int c = 0; c < 4; ++c) o_acc[c] = (f32x4){0.f, 0.f, 0.f, 0.f};

  int skey = tid >> 3, spart = tid & 7;      // K staging
  int vch = tid >> 2, vkq = (tid & 3) * 16;  // V staging

  int kbeg = split * 1024;
  for (int kt0 = kbeg; kt0 < kbeg + 1024; kt0 += 64) {
    __syncthreads();
#pragma unroll
    for (int ps = 0; ps < 2; ++ps) {
      int kk = ps * 32 + skey;
      *(uint4*)&Ks[kk * 72 + spart * 8] =
          *(const uint4*)&K[(size_t)(kt0 + kk) * 64 + spart * 8];
    }
#pragma unroll
    for (int u = 0; u < 4; ++u) {
      float4 v4 = *(const float4*)&Vg[(size_t)vch * NPOS + kt0 + vkq + u * 4];
      ushort4 pk;
      pk.x = f2bf(v4.x); pk.y = f2bf(v4.y); pk.z = f2bf(v4.z); pk.w = f2bf(v4.w);
      *(ushort4*)&Vs[vch * 72 + vkq + u * 4] = pk;
    }
    __syncthreads();
    f32x4 s_acc[4];
#pragma unroll
    for (int n = 0; n < 4; ++n) s_acc[n] = (f32x4){0.f, 0.f, 0.f, 0.f};
#pragma unroll
    for (int n = 0; n < 4; ++n)
#pragma unroll
      for (int ks = 0; ks < 2; ++ks) {
        bf16x8 kf = *(const bf16x8*)&Ks[(n * 16 + ll) * 72 + ks * 32 + lg * 8];
        s_acc[n] = __builtin_amdgcn_mfma_f32_16x16x32_bf16(qf[ks], kf, s_acc[n], 0, 0, 0);
      }
    float f_r[4];
#pragma unroll
    for (int r = 0; r < 4; ++r) {
      float mx = fmaxf(fmaxf(s_acc[0][r], s_acc[1][r]),
                       fmaxf(s_acc[2][r], s_acc[3][r])) * 0.125f;
#pragma unroll
      for (int d = 8; d >= 1; d >>= 1) mx = fmaxf(mx, __shfl_xor(mx, d));
      float mn = fmaxf(m_r[r], mx);
      f_r[r] = __expf(m_r[r] - mn);
      m_r[r] = mn;
      float rs = 0.f;
#pragma unroll
      for (int n = 0; n < 4; ++n) {
        float p = __expf(s_acc[n][r] * 0.125f - mn);
        s_acc[n][r] = p;
        rs += p;
      }
#pragma unroll
      for (int d = 8; d >= 1; d >>= 1) rs += __shfl_xor(rs, d);
      l_r[r] = l_r[r] * f_r[r] + rs;
#pragma unroll
      for (int c = 0; c < 4; ++c) o_acc[c][r] *= f_r[r];
    }
#pragma unroll
    for (int r = 0; r < 4; ++r)
#pragma unroll
      for (int n = 0; n < 4; ++n)
        Ps[wv][(lg * 4 + r) * 72 + n * 16 + ll] = f2bf(s_acc[n][r]);
#pragma unroll
    for (int ks = 0; ks < 2; ++ks) {
      bf16x8 pa = *(const bf16x8*)&Ps[wv][ll * 72 + ks * 32 + lg * 8];
#pragma unroll
      for (int c = 0; c < 4; ++c) {
        bf16x8 vf = *(const bf16x8*)&Vs[(c * 16 + ll) * 72 + ks * 32 + lg * 8];
        o_acc[c] = __builtin_amdgcn_mfma_f32_16x16x32_bf16(pa, vf, o_acc[c], 0, 0, 0);
      }
    }
  }
  size_t ob = (size_t)(b * 4 + split) * 4096;
#pragma unroll
  for (int r = 0; r < 4; ++r) {
    int q = qw + lg * 4 + r;
#pragma unroll
    for (int c = 0; c < 4; ++c)
      opart[(ob + q) * 64 + c * 16 + ll] = o_acc[c][r];
    if (ll == 0) {
      ml[(ob + q) * 2]     = m_r[r];
      ml[(ob + q) * 2 + 1] = l_r[r];
    }
  }
}

// Merge 4 split partials -> bf16 att [b][pos][192+ch]. grid 4096 blocks x 256.
__global__ __launch_bounds__(256) void combine3(const float* __restrict__ opart,
                                                const float* __restrict__ ml,
                                                unsigned short* __restrict__ attbf) {
  int bid = blockIdx.x;
  int b = bid >> 10, qt4 = bid & 1023;
  int q = qt4 * 4 + (threadIdx.x >> 6), ch = threadIdx.x & 63;
  float ms[4], ls[4];
  float M = -3.0e38f;
#pragma unroll
  for (int s = 0; s < 4; ++s) {
    size_t r = ((size_t)(b * 4 + s) * 4096 + q) * 2;
    ms[s] = ml[r]; ls[s] = ml[r + 1];
    M = fmaxf(M, ms[s]);
  }
  float num = 0.f, den = 0.f;
#pragma unroll
  for (int s = 0; s < 4; ++s) {
    float w = __expf(ms[s] - M);
    num += w * opart[((size_t)(b * 4 + s) * 4096 + q) * 64 + ch];
    den += w * ls[s];
  }
  attbf[((size_t)b * 4096 + q) * 256 + 192 + ch] = f2bf(num / den);
}

// ---------------------------------------------------------------------------
// Wo [o][c][ky][kx] fp32 -> W2 [k=ky*3+kx][o][c] bf16
__global__ __launch_bounds__(256) void transpose_wo_bf(const float* __restrict__ Wo,
                                                       unsigned short* __restrict__ W2) {
  int idx = blockIdx.x * 256 + threadIdx.x;  // 589824 total
  int o = idx / 2304, r = idx % 2304;
  int c = r / 9, k = r % 9;
  W2[(size_t)k * 65536 + (size_t)o * 256 + c] = f2bf(Wo[idx]);
}

// 3x3 SAME conv (bf16 MFMA implicit GEMM) + BN + LeakyReLU(0.2).
// grid (32 h-pairs, 4 o-tiles, 4 b), 256 threads (4 waves).
__global__ __launch_bounds__(256) void conv_mfma(
    const unsigned short* __restrict__ attbf, const unsigned short* __restrict__ w2,
    const float* __restrict__ bo, const float* __restrict__ gamma,
    const float* __restrict__ beta, const float* __restrict__ rmean,
    const float* __restrict__ rvar, float* __restrict__ out) {
  int hp = blockIdx.x, ot = blockIdx.y, b = blockIdx.z;
  int h0 = hp * 2, o0 = ot * 64;
  __shared__ unsigned short As[2 * 66 * 72];   // [rowl][w(-1..64)+1][c 0..63]
  __shared__ unsigned short Ws[3 * 64 * 72];   // [dx][o_local][c 0..63]
  int tid = threadIdx.x;
  int wi = tid >> 6, l = tid & 63;
  int hrow = wi >> 1, wseg = wi & 1;
  int lg = l >> 4, ll = l & 15;
  const size_t attb = (size_t)b * NPOS * 256;
  f32x4 acc[4][2];
#pragma unroll
  for (int mi = 0; mi < 4; ++mi)
#pragma unroll
    for (int ni = 0; ni < 2; ++ni) acc[mi][ni] = (f32x4){0.f, 0.f, 0.f, 0.f};

  for (int dy = 0; dy < 3; ++dy) {
    for (int c0 = 0; c0 < 256; c0 += 64) {
      __syncthreads();
      if (tid < 128) {
        int rowl = tid >> 6, w = tid & 63;
        int ghh = h0 + dy - 1 + rowl;
        uint4 z = make_uint4(0u, 0u, 0u, 0u);
        uint4 a[8];
        if (ghh >= 0 && ghh < 64) {
          const uint4* src = (const uint4*)(attbf + attb + ((size_t)(ghh * 64 + w) * 256 + c0));
#pragma unroll
          for (int q = 0; q < 8; ++q) a[q] = src[q];
        } else {
#pragma unroll
          for (int q = 0; q < 8; ++q) a[q] = z;
        }
        uint4* dst = (uint4*)&As[(rowl * 66 + 1 + w) * 72];
#pragma unroll
        for (int q = 0; q < 8; ++q) dst[q] = a[q];
        if (w == 0 || w == 63) {
          uint4* dz = (uint4*)&As[(rowl * 66 + ((w == 0) ? 0 : 65)) * 72];
#pragma unroll
          for (int q = 0; q < 8; ++q) dz[q] = z;
        }
      }
      if (tid >= 64) {
        int p = tid - 64;
        int dx = p >> 6, ol = p & 63;
        const uint4* src = (const uint4*)(w2 + ((size_t)(dy * 3 + dx) * 65536 +
                                                (size_t)(o0 + ol) * 256 + c0));
        uint4* dst = (uint4*)&Ws[(dx * 64 + ol) * 72];
#pragma unroll
        for (int q = 0; q < 8; ++q) dst[q] = src[q];
      }
      __syncthreads();
#pragma unroll
      for (int dx = 0; dx < 3; ++dx) {
#pragma unroll
        for (int ks = 0; ks < 2; ++ks) {
          bf16x8 af[4];
#pragma unroll
          for (int mi = 0; mi < 4; ++mi)
            af[mi] = *(const bf16x8*)&Ws[(dx * 64 + mi * 16 + ll) * 72 + ks * 32 + lg * 8];
#pragma unroll
          for (int ni = 0; ni < 2; ++ni) {
            bf16x8 bfr = *(const bf16x8*)&As[(hrow * 66 + wseg * 32 + ni * 16 + ll + dx) * 72 +
                                             ks * 32 + lg * 8];
#pragma unroll
            for (int mi = 0; mi < 4; ++mi)
              acc[mi][ni] = __builtin_amdgcn_mfma_f32_16x16x32_bf16(af[mi], bfr, acc[mi][ni],
                                                                    0, 0, 0);
          }
        }
      }
    }
  }
  int h = h0 + hrow;
#pragma unroll
  for (int mi = 0; mi < 4; ++mi) {
#pragma unroll
    for (int r = 0; r < 4; ++r) {
      int o = o0 + mi * 16 + lg * 4 + r;
      float g  = gamma[o] * rsqrtf(rvar[o] + 1e-5f);
      float bb = (bo[o] - rmean[o]) * g + beta[o];
#pragma unroll
      for (int ni = 0; ni < 2; ++ni) {
        float zv = acc[mi][ni][r] * g + bb;
        zv = (zv >= 0.f) ? zv : 0.2f * zv;
        out[((size_t)(b * 256 + o)) * NPOS + h * 64 + wseg * 32 + ni * 16 + ll] = zv;
      }
    }
  }
}

// ---------------------------------------------------------------------------
extern "C" void kernel_launch(void* const* d_in, const int* in_sizes, int n_in,
                              void* d_out, int out_size, void* d_ws, size_t ws_size,
                              hipStream_t stream) {
  (void)in_sizes; (void)n_in; (void)out_size; (void)ws_size;
  const float* x     = (const float*)d_in[0];
  const float* Wq    = (const float*)d_in[1];
  const float* bq    = (const float*)d_in[2];
  const float* Wk    = (const float*)d_in[3];
  const float* bk    = (const float*)d_in[4];
  const float* Wv    = (const float*)d_in[5];
  const float* bv    = (const float*)d_in[6];
  const float* Wo    = (const float*)d_in[7];
  const float* bo    = (const float*)d_in[8];
  const float* gamma = (const float*)d_in[9];
  const float* beta  = (const float*)d_in[10];
  const float* rmean = (const float*)d_in[11];
  const float* rvar  = (const float*)d_in[12];
  float* ws  = (float*)d_ws;
  float* out = (float*)d_out;
  unsigned short* attbf = (unsigned short*)(ws + AOFF);
  unsigned short* w2bf  = (unsigned short*)(ws + WTOFF);
  unsigned short* qt3   = (unsigned short*)(ws + QT3OFF);
  unsigned short* kt3   = (unsigned short*)(ws + KT3OFF);

  hipMemsetAsync(ws + S0OFF, 0, (size_t)4 * 64 * 64 * sizeof(float), stream);
  transpose_wo_bf<<<2304, 256, 0, stream>>>(Wo, w2bf);
  qkv_mfma<<<dim3(64, 4, 12), 256, 0, stream>>>(x, Wq, Wk, Wv, bq, bk, bv, ws);

  score_kernel<0, 8, 8, 8><<<dim3(4, 1, 8),   256, 0, stream>>>(ws, ws + S0OFF);
  score_kernel<1, 4, 4, 1><<<dim3(4, 16, 1),  256, 0, stream>>>(ws, ws + S1OFF);
  score_kernel<2, 2, 2, 1><<<dim3(4, 256, 1), 256, 0, stream>>>(ws, ws + S2OFF);

  softmax_kernel<<<4 * 64,   256, 0, stream>>>(ws + S0OFF, 64);
  softmax_kernel<<<4 * 256,  256, 0, stream>>>(ws + S1OFF, 256);
  softmax_kernel<<<4 * 1024, 256, 0, stream>>>(ws + S2OFF, 1024);

  pv_kernel<0, 8, 8><<<dim3(4, 64), 256, 0, stream>>>(ws, ws + S0OFF, attbf);
  pv_kernel<1, 4, 4><<<dim3(4, 64), 256, 0, stream>>>(ws, ws + S1OFF, attbf);
  pv_kernel<2, 2, 2><<<dim3(4, 64), 256, 0, stream>>>(ws, ws + S2OFF, attbf);

  // head 3: prep reads Q/K fp32 (then those regions become scratch for partials)
  prep_qk3<<<dim3(64, 4, 2), 256, 0, stream>>>(ws, qt3, kt3);
  flash3_split<<<dim3(4, 64, 4), 256, 0, stream>>>(ws, qt3, kt3, ws + OPOFF, ws + MLOFF);
  combine3<<<4096, 256, 0, stream>>>(ws + OPOFF, ws + MLOFF, attbf);

  conv_mfma<<<dim3(32, 4, 4), 256, 0, stream>>>(attbf, w2bf, bo, gamma, beta,
                                                rmean, rvar, out);
}

// Round 6
// 360.277 us; speedup vs baseline: 3.2188x; 1.1202x over previous
//
#include <hip/hip_runtime.h>
#include <math.h>

// Problem constants: b=4, C=256, H=W=64
#define NPOS 4096            // 64*64 spatial positions
#define CPB  1048576         // C*NPOS, per-batch stride in fp32 q/k/v
// ws layout (float offsets)
#define QOFF  ((size_t)0)          // fp32 q; after preps: v_t (bf16, 2.097M floats) + ml3
#define KOFF  ((size_t)4194304)    // fp32 k; after preps: head3 opart (4.19M floats)
#define VOFF  ((size_t)8388608)    // fp32 v
#define AOFF  ((size_t)12582912)   // bf16 att, [b][pos][c], 4*4096*256 ushort
#define S0OFF ((size_t)16777216)   // q_t (2.097M fl) + k_t (2.097M fl) + Spart (131K fl)
#define WTOFF ((size_t)21250048)   // bf16 W2 [k][o][c], 9*256*256 ushort
// derived regions
#define QTOFF  S0OFF                       // q_t bf16 all heads: [(b*4+h)*262144] ush
#define KTOFF  (S0OFF + (size_t)2097152)   // k_t bf16
#define SPOFF  (S0OFF + (size_t)4194304)   // head0 partial S: 4b*8ds*64*64 fp32 = 131072 fl
#define VTOFF  QOFF                        // v_t bf16 all heads (after q/k preps)
#define ML3OFF (QOFF + (size_t)2097152)    // head3 (m,l): 4b*4s*4096*2 = 131072 fl
#define OP3OFF KOFF                        // head3 partial O: 4*4*4096*64 fl

typedef __attribute__((ext_vector_type(8))) short bf16x8;
typedef __attribute__((ext_vector_type(4))) float f32x4;

static __device__ __forceinline__ unsigned short f2bf(float f) {
  union { float f; unsigned u; } v; v.f = f;
  unsigned u = v.u;
  return (unsigned short)((u + 0x7FFFu + ((u >> 16) & 1u)) >> 16);
}

// ---------------------------------------------------------------------------
// QKV 1x1-conv projections via bf16 MFMA, fp32 out. (proven round 5)
__global__ __launch_bounds__(256) void qkv_mfma(
    const float* __restrict__ x,
    const float* __restrict__ Wq, const float* __restrict__ Wk, const float* __restrict__ Wv,
    const float* __restrict__ bq, const float* __restrict__ bk, const float* __restrict__ bv,
    float* __restrict__ ws) {
  int b = blockIdx.z / 3, t = blockIdx.z % 3;
  const float* W    = (t == 0) ? Wq : (t == 1) ? Wk : Wv;
  const float* bias = (t == 0) ? bq : (t == 1) ? bk : bv;
  float* outp = ws + (size_t)t * 4194304 + (size_t)b * CPB;
  int o0 = blockIdx.y * 64, p0 = blockIdx.x * 64;
  __shared__ unsigned short Wt[64 * 72];  // [o_local][c 0..63]
  __shared__ unsigned short Xs[64 * 72];  // [p_local][c 0..63]
  int tid = threadIdx.x;
  int wv = tid >> 6, l = tid & 63;
  int lg = l >> 4, ll = l & 15;
  f32x4 acc[4];
#pragma unroll
  for (int mi = 0; mi < 4; ++mi) acc[mi] = (f32x4){0.f, 0.f, 0.f, 0.f};

  int wol = tid >> 2, wcp = (tid & 3) * 16;
  int xcc = tid >> 6, xpz = tid & 63;

  for (int c0 = 0; c0 < 256; c0 += 64) {
    __syncthreads();
#pragma unroll
    for (int u = 0; u < 4; ++u) {
      float4 w4 = *(const float4*)&W[(size_t)(o0 + wol) * 256 + c0 + wcp + u * 4];
      ushort4 pk;
      pk.x = f2bf(w4.x); pk.y = f2bf(w4.y); pk.z = f2bf(w4.z); pk.w = f2bf(w4.w);
      *(ushort4*)&Wt[wol * 72 + wcp + u * 4] = pk;
    }
#pragma unroll
    for (int r = 0; r < 16; ++r) {
      int c = xcc * 16 + r;
      Xs[xpz * 72 + c] = f2bf(x[(size_t)b * CPB + (size_t)(c0 + c) * NPOS + p0 + xpz]);
    }
    __syncthreads();
#pragma unroll
    for (int ks = 0; ks < 2; ++ks) {
      bf16x8 xb = *(const bf16x8*)&Xs[(wv * 16 + ll) * 72 + ks * 32 + lg * 8];
#pragma unroll
      for (int mi = 0; mi < 4; ++mi) {
        bf16x8 wa = *(const bf16x8*)&Wt[(mi * 16 + ll) * 72 + ks * 32 + lg * 8];
        acc[mi] = __builtin_amdgcn_mfma_f32_16x16x32_bf16(wa, xb, acc[mi], 0, 0, 0);
      }
    }
  }
#pragma unroll
  for (int mi = 0; mi < 4; ++mi)
#pragma unroll
    for (int r = 0; r < 4; ++r) {
      int o = o0 + mi * 16 + lg * 4 + r;
      outp[(size_t)o * NPOS + p0 + wv * 16 + ll] = acc[mi][r] + bias[o];
    }
}

// ---------------------------------------------------------------------------
// Prep q/k -> bf16 token-major [t][D] for heads 0..2. grid (128, 4b, 2tns).
// Dest-linear: each thread writes one uint4 (8 consecutive d); reads scattered L2-hot fp32.
template<int PH, int PW, int HEAD>
__global__ __launch_bounds__(256) void prep_qk_direct(const float* __restrict__ qsrc,
                                                      const float* __restrict__ ksrc,
                                                      unsigned short* __restrict__ qt,
                                                      unsigned short* __restrict__ kt_) {
  constexpr int PP = PH * PW, D = 64 * PP, OW = 64 / PW;
  int b = blockIdx.y, tns = blockIdx.z;
  const float* src = (tns ? ksrc : qsrc) + (size_t)b * CPB + (size_t)HEAD * 64 * NPOS;
  unsigned short* dst = (tns ? kt_ : qt) + ((size_t)b * 4 + HEAD) * 262144;
  int idx = blockIdx.x * 256 + threadIdx.x;     // [0, 32768)
  int t = idx / (D / 8), j8 = idx % (D / 8);
  int po = t / OW, qo = t % OW;
  union { unsigned short u16[8]; uint4 v; } pk;
#pragma unroll
  for (int e = 0; e < 8; ++e) {
    int d = j8 * 8 + e;
    int c = d / PP, rem = d % PP, y = rem / PW, x = rem % PW;
    pk.u16[e] = f2bf(src[(size_t)c * NPOS + (po * PH + y) * 64 + qo * PW + x]);
  }
  *(uint4*)&dst[(size_t)t * D + j8 * 8] = pk.v;
}

// Head-3 q/k prep (proven): fp32 [ch][pos] -> bf16 token-major [pos][64ch].
__global__ __launch_bounds__(256) void prep_qk3(const float* __restrict__ ws_,
                                                unsigned short* __restrict__ qt,
                                                unsigned short* __restrict__ kt_) {
  int pt = blockIdx.x, b = blockIdx.y, t = blockIdx.z;
  const float* src = ws_ + (t ? KOFF : QOFF) + (size_t)b * CPB + (size_t)192 * NPOS + pt * 64;
  unsigned short* dst = (t ? kt_ : qt) + ((size_t)b * 4 + 3) * 262144 + (size_t)pt * 4096;
  __shared__ float tile[64][65];
  int tid = threadIdx.x;
  int a = tid >> 6, pz = tid & 63;
#pragma unroll
  for (int r = 0; r < 16; ++r) {
    int ch = a + r * 4;
    tile[pz][ch] = src[(size_t)ch * NPOS + pz];
  }
  __syncthreads();
  int ch2 = tid & 63, pr = tid >> 6;
#pragma unroll
  for (int r = 0; r < 16; ++r) {
    int pos = pr + r * 4;
    dst[(size_t)pos * 64 + ch2] = f2bf(tile[pos][ch2]);
  }
}

// Prep v -> bf16 dim-major [d][n] for all heads. grid (128, 4b). Head3 = pure cast.
template<int PH, int PW, int HEAD>
__global__ __launch_bounds__(256) void prep_v_direct(const float* __restrict__ vsrc,
                                                     unsigned short* __restrict__ vt) {
  constexpr int PP = PH * PW, NT = NPOS / PP, OW = 64 / PW;
  int b = blockIdx.y;
  const float* src = vsrc + (size_t)b * CPB + (size_t)HEAD * 64 * NPOS;
  unsigned short* dst = vt + ((size_t)b * 4 + HEAD) * 262144;
  int idx = blockIdx.x * 256 + threadIdx.x;     // [0, 32768)
  int d = idx / (NT / 8), j8 = idx % (NT / 8);
  int c = d / PP, rem = d % PP, y = rem / PW, x = rem % PW;
  union { unsigned short u16[8]; uint4 v; } pk;
#pragma unroll
  for (int e = 0; e < 8; ++e) {
    int t = j8 * 8 + e;
    int po = t / OW, qo = t % OW;
    pk.u16[e] = f2bf(src[(size_t)c * NPOS + (po * PH + y) * 64 + qo * PW + x]);
  }
  *(uint4*)&dst[(size_t)d * NT + j8 * 8] = pk.v;
}

// ---------------------------------------------------------------------------
// Generic MFMA flash attention (fragment algebra identical to proven flash3):
// A-frag row=l&15, k=(l>>4)*8; D: col=l&15, row=(l>>4)*4+reg.
// grid (4b, NTOK/64, NSPLIT), 4 waves; wave owns 16 queries.
template<int NTOK, int DDIM, int NSPLIT, int KVB, int PH, int PW, int HEAD>
__global__ __launch_bounds__(256) void flash_attn(
    const unsigned short* __restrict__ qt, const unsigned short* __restrict__ kt_,
    const unsigned short* __restrict__ vt, float* __restrict__ opart,
    float* __restrict__ ml, unsigned short* __restrict__ attbf) {
  constexpr int KSTR = DDIM + 8;   // Ks row stride (ush)
  constexpr int VSTR = KVB + 8;    // Vs/Ps row stride
  constexpr int NT   = KVB / 16;   // key tiles per kv-block
  constexpr int KCH  = DDIM / 32;  // QK k-steps
  constexpr int PKS  = KVB / 32;   // PV k-steps
  constexpr int OCG  = DDIM / 16;  // output col groups
  constexpr float scale = (DDIM == 64) ? 0.125f : (DDIM == 256) ? 0.0625f
                        : (DDIM == 1024) ? 0.03125f : 0.015625f;
  constexpr int PP = PH * PW, OW = 64 / PW;
  int b = blockIdx.x, q0 = blockIdx.y * 64, split = blockIdx.z;
  const unsigned short* Q = qt + ((size_t)b * 4 + HEAD) * 262144;
  const unsigned short* K = kt_ + ((size_t)b * 4 + HEAD) * 262144;
  const unsigned short* V = vt + ((size_t)b * 4 + HEAD) * 262144;
  __shared__ unsigned short Ks[KVB * KSTR];
  __shared__ unsigned short Vs[DDIM * VSTR];
  __shared__ unsigned short Ps[4][16 * VSTR];
  int tid = threadIdx.x;
  int wv = tid >> 6, l = tid & 63;
  int lg = l >> 4, ll = l & 15;
  int qw = q0 + wv * 16;

  bf16x8 qf[KCH];
#pragma unroll
  for (int kc = 0; kc < KCH; ++kc)
    qf[kc] = *(const bf16x8*)&Q[(size_t)(qw + ll) * DDIM + kc * 32 + lg * 8];

  float m_r[4] = {-3.0e38f, -3.0e38f, -3.0e38f, -3.0e38f};
  float l_r[4] = {0.f, 0.f, 0.f, 0.f};
  f32x4 o_acc[OCG];
#pragma unroll
  for (int c = 0; c < OCG; ++c) o_acc[c] = (f32x4){0.f, 0.f, 0.f, 0.f};

  for (int kt0 = split * (NTOK / NSPLIT); kt0 < (split + 1) * (NTOK / NSPLIT); kt0 += KVB) {
    __syncthreads();
#pragma unroll
    for (int i = 0; i < KVB * DDIM / 2048; ++i) {
      int u = i * 256 + tid;
      int key = u / (DDIM / 8), part = u % (DDIM / 8);
      *(uint4*)&Ks[key * KSTR + part * 8] =
          *(const uint4*)&K[(size_t)(kt0 + key) * DDIM + part * 8];
    }
#pragma unroll
    for (int i = 0; i < KVB * DDIM / 2048; ++i) {
      int u = i * 256 + tid;
      int d = u / (KVB / 8), part = u % (KVB / 8);
      *(uint4*)&Vs[d * VSTR + part * 8] =
          *(const uint4*)&V[(size_t)d * NTOK + kt0 + part * 8];
    }
    __syncthreads();
    f32x4 s_acc[NT];
#pragma unroll
    for (int n = 0; n < NT; ++n) s_acc[n] = (f32x4){0.f, 0.f, 0.f, 0.f};
#pragma unroll
    for (int n = 0; n < NT; ++n)
#pragma unroll
      for (int kc = 0; kc < KCH; ++kc) {
        bf16x8 kf = *(const bf16x8*)&Ks[(n * 16 + ll) * KSTR + kc * 32 + lg * 8];
        s_acc[n] = __builtin_amdgcn_mfma_f32_16x16x32_bf16(qf[kc], kf, s_acc[n], 0, 0, 0);
      }
    float f_r[4];
#pragma unroll
    for (int r = 0; r < 4; ++r) {
      float mx = -3.0e38f;
#pragma unroll
      for (int n = 0; n < NT; ++n) mx = fmaxf(mx, s_acc[n][r]);
      mx *= scale;
#pragma unroll
      for (int d = 8; d >= 1; d >>= 1) mx = fmaxf(mx, __shfl_xor(mx, d));
      float mn = fmaxf(m_r[r], mx);
      f_r[r] = __expf(m_r[r] - mn);
      m_r[r] = mn;
      float rs = 0.f;
#pragma unroll
      for (int n = 0; n < NT; ++n) {
        float p = __expf(s_acc[n][r] * scale - mn);
        s_acc[n][r] = p;
        rs += p;
      }
#pragma unroll
      for (int d = 8; d >= 1; d >>= 1) rs += __shfl_xor(rs, d);
      l_r[r] = l_r[r] * f_r[r] + rs;
#pragma unroll
      for (int c = 0; c < OCG; ++c) o_acc[c][r] *= f_r[r];
    }
#pragma unroll
    for (int r = 0; r < 4; ++r)
#pragma unroll
      for (int n = 0; n < NT; ++n)
        Ps[wv][(lg * 4 + r) * VSTR + n * 16 + ll] = f2bf(s_acc[n][r]);
#pragma unroll
    for (int pk = 0; pk < PKS; ++pk) {
      bf16x8 pa = *(const bf16x8*)&Ps[wv][ll * VSTR + pk * 32 + lg * 8];
#pragma unroll
      for (int c = 0; c < OCG; ++c) {
        bf16x8 vf = *(const bf16x8*)&Vs[(c * 16 + ll) * VSTR + pk * 32 + lg * 8];
        o_acc[c] = __builtin_amdgcn_mfma_f32_16x16x32_bf16(pa, vf, o_acc[c], 0, 0, 0);
      }
    }
  }
  if constexpr (NSPLIT > 1) {
    size_t ob = (size_t)(b * NSPLIT + split) * NTOK;
#pragma unroll
    for (int r = 0; r < 4; ++r) {
      int q = qw + lg * 4 + r;
#pragma unroll
      for (int c = 0; c < OCG; ++c)
        opart[(ob + q) * DDIM + c * 16 + ll] = o_acc[c][r];
      if (ll == 0) {
        ml[(ob + q) * 2]     = m_r[r];
        ml[(ob + q) * 2 + 1] = l_r[r];
      }
    }
  } else {
#pragma unroll
    for (int r = 0; r < 4; ++r) {
      float inv = 1.0f / l_r[r];
      int q = qw + lg * 4 + r;
      int po = q / OW, qo = q % OW;
#pragma unroll
      for (int c = 0; c < OCG; ++c) {
        int d = c * 16 + ll;
        int ch = d / PP, rem = d % PP, y = rem / PW, x = rem % PW;
        int pos = (po * PH + y) * 64 + qo * PW + x;
        attbf[((size_t)b * NPOS + pos) * 256 + HEAD * 64 + ch] = f2bf(o_acc[c][r] * inv);
      }
    }
  }
}

// Merge head-3 split partials -> bf16 att. grid 4096 x 256. (proven)
__global__ __launch_bounds__(256) void combine3(const float* __restrict__ opart,
                                                const float* __restrict__ ml,
                                                unsigned short* __restrict__ attbf) {
  int bid = blockIdx.x;
  int b = bid >> 10, qt4 = bid & 1023;
  int q = qt4 * 4 + (threadIdx.x >> 6), ch = threadIdx.x & 63;
  float ms[4], ls[4];
  float M = -3.0e38f;
#pragma unroll
  for (int s = 0; s < 4; ++s) {
    size_t r = ((size_t)(b * 4 + s) * 4096 + q) * 2;
    ms[s] = ml[r]; ls[s] = ml[r + 1];
    M = fmaxf(M, ms[s]);
  }
  float num = 0.f, den = 0.f;
#pragma unroll
  for (int s = 0; s < 4; ++s) {
    float w = __expf(ms[s] - M);
    num += w * opart[((size_t)(b * 4 + s) * 4096 + q) * 64 + ch];
    den += w * ls[s];
  }
  attbf[((size_t)b * 4096 + q) * 256 + 192 + ch] = f2bf(num / den);
}

// ---------------------------------------------------------------------------
// Head 0 (n=64, D=4096): partial-S kernel. grid (4b, 8 d-slices).
__global__ __launch_bounds__(256) void h0_score(const unsigned short* __restrict__ qt,
                                                const unsigned short* __restrict__ kt_,
                                                float* __restrict__ spart) {
  int b = blockIdx.x, ds = blockIdx.y;
  const unsigned short* Q = qt + ((size_t)b * 4 + 0) * 262144;
  const unsigned short* K = kt_ + ((size_t)b * 4 + 0) * 262144;
  __shared__ unsigned short Qc[64 * 72], Kc[64 * 72];
  int tid = threadIdx.x;
  int wv = tid >> 6, l = tid & 63;
  int lg = l >> 4, ll = l & 15;
  f32x4 s_acc[4];
#pragma unroll
  for (int n = 0; n < 4; ++n) s_acc[n] = (f32x4){0.f, 0.f, 0.f, 0.f};
  for (int ch = 0; ch < 8; ++ch) {
    int d0 = ds * 512 + ch * 64;
    __syncthreads();
#pragma unroll
    for (int i = 0; i < 2; ++i) {
      int u = i * 256 + tid, row = u >> 3, part = u & 7;
      *(uint4*)&Qc[row * 72 + part * 8] = *(const uint4*)&Q[(size_t)row * 4096 + d0 + part * 8];
      *(uint4*)&Kc[row * 72 + part * 8] = *(const uint4*)&K[(size_t)row * 4096 + d0 + part * 8];
    }
    __syncthreads();
#pragma unroll
    for (int n = 0; n < 4; ++n)
#pragma unroll
      for (int ks = 0; ks < 2; ++ks) {
        bf16x8 qa = *(const bf16x8*)&Qc[(wv * 16 + ll) * 72 + ks * 32 + lg * 8];
        bf16x8 kf = *(const bf16x8*)&Kc[(n * 16 + ll) * 72 + ks * 32 + lg * 8];
        s_acc[n] = __builtin_amdgcn_mfma_f32_16x16x32_bf16(qa, kf, s_acc[n], 0, 0, 0);
      }
  }
#pragma unroll
  for (int n = 0; n < 4; ++n)
#pragma unroll
    for (int r = 0; r < 4; ++r)
      spart[(((size_t)b * 8 + ds) * 64 + (wv * 16 + lg * 4 + r)) * 64 + n * 16 + ll] =
          s_acc[n][r];
}

// Head 0 finish: sum partials, exact softmax, PV over this block's 512-d slice.
__global__ __launch_bounds__(256) void h0_pv(const float* __restrict__ spart,
                                             const unsigned short* __restrict__ vt,
                                             unsigned short* __restrict__ attbf) {
  int b = blockIdx.x, ds = blockIdx.y;
  const unsigned short* V = vt + ((size_t)b * 4 + 0) * 262144;
  __shared__ float S[64 * 65];
  __shared__ unsigned short Ps[64 * 72];
  __shared__ unsigned short Vc[64 * 72];
  int tid = threadIdx.x;
  int wv = tid >> 6, l = tid & 63;
  int lg = l >> 4, ll = l & 15;
#pragma unroll
  for (int i = 0; i < 16; ++i) {
    int idx = i * 256 + tid, q = idx >> 6, k = idx & 63;
    float s = 0.f;
#pragma unroll
    for (int sl = 0; sl < 8; ++sl)
      s += spart[(((size_t)b * 8 + sl) * 64 + q) * 64 + k];
    S[q * 65 + k] = s;
  }
  __syncthreads();
  for (int rr = 0; rr < 16; ++rr) {
    int row = wv * 16 + rr;
    float v = S[row * 65 + l] * 0.015625f;
    float m = v;
#pragma unroll
    for (int d = 32; d >= 1; d >>= 1) m = fmaxf(m, __shfl_xor(m, d));
    float p = __expf(v - m);
    float su = p;
#pragma unroll
    for (int d = 32; d >= 1; d >>= 1) su += __shfl_xor(su, d);
    Ps[row * 72 + l] = f2bf(p / su);
  }
  __syncthreads();
  for (int ch = 0; ch < 8; ++ch) {
    int d0 = ds * 512 + ch * 64;
    __syncthreads();
#pragma unroll
    for (int i = 0; i < 2; ++i) {
      int u = i * 256 + tid, row = u >> 3, part = u & 7;
      *(uint4*)&Vc[row * 72 + part * 8] =
          *(const uint4*)&V[(size_t)(d0 + row) * 64 + part * 8];
    }
    __syncthreads();
    f32x4 o[4];
#pragma unroll
    for (int cg = 0; cg < 4; ++cg) o[cg] = (f32x4){0.f, 0.f, 0.f, 0.f};
#pragma unroll
    for (int cg = 0; cg < 4; ++cg)
#pragma unroll
      for (int ks = 0; ks < 2; ++ks) {
        bf16x8 pa = *(const bf16x8*)&Ps[(wv * 16 + ll) * 72 + ks * 32 + lg * 8];
        bf16x8 vf = *(const bf16x8*)&Vc[(cg * 16 + ll) * 72 + ks * 32 + lg * 8];
        o[cg] = __builtin_amdgcn_mfma_f32_16x16x32_bf16(pa, vf, o[cg], 0, 0, 0);
      }
#pragma unroll
    for (int cg = 0; cg < 4; ++cg)
#pragma unroll
      for (int r = 0; r < 4; ++r) {
        int q = wv * 16 + lg * 4 + r;
        int d = d0 + cg * 16 + ll;
        int c = d >> 6, rem = d & 63, y = rem >> 3, x = rem & 7;
        int po = q >> 3, qo = q & 7;
        int pos = (po * 8 + y) * 64 + qo * 8 + x;
        attbf[((size_t)b * NPOS + pos) * 256 + c] = f2bf(o[cg][r]);
      }
  }
}

// ---------------------------------------------------------------------------
// Head 1 (n=256, D=1024): one-shot, S fully in registers. grid (4b, 4 q-tiles).
__global__ __launch_bounds__(256) void h1_attn(const unsigned short* __restrict__ qt,
                                               const unsigned short* __restrict__ kt_,
                                               const unsigned short* __restrict__ vt,
                                               unsigned short* __restrict__ attbf) {
  int b = blockIdx.x, q0 = blockIdx.y * 64;
  const unsigned short* Q = qt + ((size_t)b * 4 + 1) * 262144;
  const unsigned short* K = kt_ + ((size_t)b * 4 + 1) * 262144;
  const unsigned short* V = vt + ((size_t)b * 4 + 1) * 262144;
  __shared__ unsigned short bufA[192 * 72];   // Qc[64][72] + Kc[128][72]; Vs[32][264] overlays
  __shared__ unsigned short Ps[64 * 264];     // normalized P bf16 [64 q][256 k]
  unsigned short* Qc = bufA;
  unsigned short* Kc = bufA + 64 * 72;
  unsigned short* Vs = bufA;
  int tid = threadIdx.x;
  int wv = tid >> 6, l = tid & 63;
  int lg = l >> 4, ll = l & 15;
  f32x4 s_acc[16];
#pragma unroll
  for (int n = 0; n < 16; ++n) s_acc[n] = (f32x4){0.f, 0.f, 0.f, 0.f};

  for (int kh = 0; kh < 2; ++kh) {
    for (int dc = 0; dc < 16; ++dc) {
      int d0 = dc * 64;
      __syncthreads();
#pragma unroll
      for (int i = 0; i < 2; ++i) {
        int u = i * 256 + tid, row = u >> 3, part = u & 7;
        *(uint4*)&Qc[row * 72 + part * 8] =
            *(const uint4*)&Q[(size_t)(q0 + row) * 1024 + d0 + part * 8];
      }
#pragma unroll
      for (int i = 0; i < 4; ++i) {
        int u = i * 256 + tid, row = u >> 3, part = u & 7;
        *(uint4*)&Kc[row * 72 + part * 8] =
            *(const uint4*)&K[(size_t)(kh * 128 + row) * 1024 + d0 + part * 8];
      }
      __syncthreads();
#pragma unroll
      for (int n8 = 0; n8 < 8; ++n8)
#pragma unroll
        for (int ks = 0; ks < 2; ++ks) {
          bf16x8 qa = *(const bf16x8*)&Qc[(wv * 16 + ll) * 72 + ks * 32 + lg * 8];
          bf16x8 kf = *(const bf16x8*)&Kc[(n8 * 16 + ll) * 72 + ks * 32 + lg * 8];
          s_acc[kh * 8 + n8] =
              __builtin_amdgcn_mfma_f32_16x16x32_bf16(qa, kf, s_acc[kh * 8 + n8], 0, 0, 0);
        }
    }
  }
  // exact softmax + normalize, P -> LDS bf16
#pragma unroll
  for (int r = 0; r < 4; ++r) {
    float mx = -3.0e38f;
#pragma unroll
    for (int n = 0; n < 16; ++n) mx = fmaxf(mx, s_acc[n][r]);
    mx *= 0.03125f;
#pragma unroll
    for (int d = 8; d >= 1; d >>= 1) mx = fmaxf(mx, __shfl_xor(mx, d));
    float rs = 0.f;
#pragma unroll
    for (int n = 0; n < 16; ++n) {
      float p = __expf(s_acc[n][r] * 0.03125f - mx);
      s_acc[n][r] = p;
      rs += p;
    }
#pragma unroll
    for (int d = 8; d >= 1; d >>= 1) rs += __shfl_xor(rs, d);
    float inv = 1.0f / rs;
#pragma unroll
    for (int n = 0; n < 16; ++n)
      Ps[(wv * 16 + lg * 4 + r) * 264 + n * 16 + ll] = f2bf(s_acc[n][r] * inv);
  }
  // PV streamed over 32-d chunks
  for (int vc = 0; vc < 32; ++vc) {
    int d0 = vc * 32;
    __syncthreads();
#pragma unroll
    for (int i = 0; i < 4; ++i) {
      int u = i * 256 + tid, row = u >> 5, part = u & 31;
      *(uint4*)&Vs[row * 264 + part * 8] =
          *(const uint4*)&V[(size_t)(d0 + row) * 256 + part * 8];
    }
    __syncthreads();
    f32x4 o[2];
    o[0] = (f32x4){0.f, 0.f, 0.f, 0.f};
    o[1] = (f32x4){0.f, 0.f, 0.f, 0.f};
#pragma unroll
    for (int cg = 0; cg < 2; ++cg)
#pragma unroll
      for (int ks = 0; ks < 8; ++ks) {
        bf16x8 pa = *(const bf16x8*)&Ps[(wv * 16 + ll) * 264 + ks * 32 + lg * 8];
        bf16x8 vf = *(const bf16x8*)&Vs[(cg * 16 + ll) * 264 + ks * 32 + lg * 8];
        o[cg] = __builtin_amdgcn_mfma_f32_16x16x32_bf16(pa, vf, o[cg], 0, 0, 0);
      }
#pragma unroll
    for (int cg = 0; cg < 2; ++cg)
#pragma unroll
      for (int r = 0; r < 4; ++r) {
        int q = q0 + wv * 16 + lg * 4 + r;
        int d = d0 + cg * 16 + ll;
        int c = d >> 4, rem = d & 15, y = rem >> 2, x = rem & 3;
        int po = q >> 4, qo = q & 15;
        int pos = (po * 4 + y) * 64 + qo * 4 + x;
        attbf[((size_t)b * NPOS + pos) * 256 + 64 + c] = f2bf(o[cg][r]);
      }
  }
}

// ---------------------------------------------------------------------------
// Wo [o][c][ky][kx] fp32 -> W2 [k=ky*3+kx][o][c] bf16
__global__ __launch_bounds__(256) void transpose_wo_bf(const float* __restrict__ Wo,
                                                       unsigned short* __restrict__ W2) {
  int idx = blockIdx.x * 256 + threadIdx.x;  // 589824 total
  int o = idx / 2304, r = idx % 2304;
  int c = r / 9, k = r % 9;
  W2[(size_t)k * 65536 + (size_t)o * 256 + c] = f2bf(Wo[idx]);
}

// 3x3 SAME conv (bf16 MFMA implicit GEMM) + BN + LeakyReLU(0.2). (proven)
__global__ __launch_bounds__(256) void conv_mfma(
    const unsigned short* __restrict__ attbf, const unsigned short* __restrict__ w2,
    const float* __restrict__ bo, const float* __restrict__ gamma,
    const float* __restrict__ beta, const float* __restrict__ rmean,
    const float* __restrict__ rvar, float* __restrict__ out) {
  int hp = blockIdx.x, ot = blockIdx.y, b = blockIdx.z;
  int h0 = hp * 2, o0 = ot * 64;
  __shared__ unsigned short As[2 * 66 * 72];
  __shared__ unsigned short Ws[3 * 64 * 72];
  int tid = threadIdx.x;
  int wi = tid >> 6, l = tid & 63;
  int hrow = wi >> 1, wseg = wi & 1;
  int lg = l >> 4, ll = l & 15;
  const size_t attb = (size_t)b * NPOS * 256;
  f32x4 acc[4][2];
#pragma unroll
  for (int mi = 0; mi < 4; ++mi)
#pragma unroll
    for (int ni = 0; ni < 2; ++ni) acc[mi][ni] = (f32x4){0.f, 0.f, 0.f, 0.f};

  for (int dy = 0; dy < 3; ++dy) {
    for (int c0 = 0; c0 < 256; c0 += 64) {
      __syncthreads();
      if (tid < 128) {
        int rowl = tid >> 6, w = tid & 63;
        int ghh = h0 + dy - 1 + rowl;
        uint4 z = make_uint4(0u, 0u, 0u, 0u);
        uint4 a[8];
        if (ghh >= 0 && ghh < 64) {
          const uint4* src = (const uint4*)(attbf + attb + ((size_t)(ghh * 64 + w) * 256 + c0));
#pragma unroll
          for (int q = 0; q < 8; ++q) a[q] = src[q];
        } else {
#pragma unroll
          for (int q = 0; q < 8; ++q) a[q] = z;
        }
        uint4* dst = (uint4*)&As[(rowl * 66 + 1 + w) * 72];
#pragma unroll
        for (int q = 0; q < 8; ++q) dst[q] = a[q];
        if (w == 0 || w == 63) {
          uint4* dz = (uint4*)&As[(rowl * 66 + ((w == 0) ? 0 : 65)) * 72];
#pragma unroll
          for (int q = 0; q < 8; ++q) dz[q] = z;
        }
      }
      if (tid >= 64) {
        int p = tid - 64;
        int dx = p >> 6, ol = p & 63;
        const uint4* src = (const uint4*)(w2 + ((size_t)(dy * 3 + dx) * 65536 +
                                                (size_t)(o0 + ol) * 256 + c0));
        uint4* dst = (uint4*)&Ws[(dx * 64 + ol) * 72];
#pragma unroll
        for (int q = 0; q < 8; ++q) dst[q] = src[q];
      }
      __syncthreads();
#pragma unroll
      for (int dx = 0; dx < 3; ++dx) {
#pragma unroll
        for (int ks = 0; ks < 2; ++ks) {
          bf16x8 af[4];
#pragma unroll
          for (int mi = 0; mi < 4; ++mi)
            af[mi] = *(const bf16x8*)&Ws[(dx * 64 + mi * 16 + ll) * 72 + ks * 32 + lg * 8];
#pragma unroll
          for (int ni = 0; ni < 2; ++ni) {
            bf16x8 bfr = *(const bf16x8*)&As[(hrow * 66 + wseg * 32 + ni * 16 + ll + dx) * 72 +
                                             ks * 32 + lg * 8];
#pragma unroll
            for (int mi = 0; mi < 4; ++mi)
              acc[mi][ni] = __builtin_amdgcn_mfma_f32_16x16x32_bf16(af[mi], bfr, acc[mi][ni],
                                                                    0, 0, 0);
          }
        }
      }
    }
  }
  int h = h0 + hrow;
#pragma unroll
  for (int mi = 0; mi < 4; ++mi) {
#pragma unroll
    for (int r = 0; r < 4; ++r) {
      int o = o0 + mi * 16 + lg * 4 + r;
      float g  = gamma[o] * rsqrtf(rvar[o] + 1e-5f);
      float bb = (bo[o] - rmean[o]) * g + beta[o];
#pragma unroll
      for (int ni = 0; ni < 2; ++ni) {
        float zv = acc[mi][ni][r] * g + bb;
        zv = (zv >= 0.f) ? zv : 0.2f * zv;
        out[((size_t)(b * 256 + o)) * NPOS + h * 64 + wseg * 32 + ni * 16 + ll] = zv;
      }
    }
  }
}

// ---------------------------------------------------------------------------
extern "C" void kernel_launch(void* const* d_in, const int* in_sizes, int n_in,
                              void* d_out, int out_size, void* d_ws, size_t ws_size,
                              hipStream_t stream) {
  (void)in_sizes; (void)n_in; (void)out_size; (void)ws_size;
  const float* x     = (const float*)d_in[0];
  const float* Wq    = (const float*)d_in[1];
  const float* bq    = (const float*)d_in[2];
  const float* Wk    = (const float*)d_in[3];
  const float* bk    = (const float*)d_in[4];
  const float* Wv    = (const float*)d_in[5];
  const float* bv    = (const float*)d_in[6];
  const float* Wo    = (const float*)d_in[7];
  const float* bo    = (const float*)d_in[8];
  const float* gamma = (const float*)d_in[9];
  const float* beta  = (const float*)d_in[10];
  const float* rmean = (const float*)d_in[11];
  const float* rvar  = (const float*)d_in[12];
  float* ws  = (float*)d_ws;
  float* out = (float*)d_out;
  unsigned short* attbf = (unsigned short*)(ws + AOFF);
  unsigned short* w2bf  = (unsigned short*)(ws + WTOFF);
  unsigned short* qt    = (unsigned short*)(ws + QTOFF);
  unsigned short* kt    = (unsigned short*)(ws + KTOFF);
  unsigned short* vt    = (unsigned short*)(ws + VTOFF);
  const float* qf32 = ws + QOFF;
  const float* kf32 = ws + KOFF;
  const float* vf32 = ws + VOFF;

  transpose_wo_bf<<<2304, 256, 0, stream>>>(Wo, w2bf);
  qkv_mfma<<<dim3(64, 4, 12), 256, 0, stream>>>(x, Wq, Wk, Wv, bq, bk, bv, ws);

  // token-major bf16 q/k for all heads (reads fp32 q/k)
  prep_qk_direct<8, 8, 0><<<dim3(128, 4, 2), 256, 0, stream>>>(qf32, kf32, qt, kt);
  prep_qk_direct<4, 4, 1><<<dim3(128, 4, 2), 256, 0, stream>>>(qf32, kf32, qt, kt);
  prep_qk_direct<2, 2, 2><<<dim3(128, 4, 2), 256, 0, stream>>>(qf32, kf32, qt, kt);
  prep_qk3<<<dim3(64, 4, 2), 256, 0, stream>>>(ws, qt, kt);
  // dim-major bf16 v for all heads (writes over dead fp32 q region)
  prep_v_direct<8, 8, 0><<<dim3(128, 4), 256, 0, stream>>>(vf32, vt);
  prep_v_direct<4, 4, 1><<<dim3(128, 4), 256, 0, stream>>>(vf32, vt);
  prep_v_direct<2, 2, 2><<<dim3(128, 4), 256, 0, stream>>>(vf32, vt);
  prep_v_direct<1, 1, 3><<<dim3(128, 4), 256, 0, stream>>>(vf32, vt);

  // head 0: partial-S + finish (32-way parallel)
  h0_score<<<dim3(4, 8), 256, 0, stream>>>(qt, kt, ws + SPOFF);
  h0_pv<<<dim3(4, 8), 256, 0, stream>>>(ws + SPOFF, vt, attbf);
  // head 1: one-shot S-in-registers
  h1_attn<<<dim3(4, 4), 256, 0, stream>>>(qt, kt, vt, attbf);
  // head 2: flash, direct write
  flash_attn<1024, 256, 1, 32, 2, 2, 2><<<dim3(4, 16, 1), 256, 0, stream>>>(
      qt, kt, vt, nullptr, nullptr, attbf);
  // head 3: split-KV flash (partials into dead fp32 k region) + combine
  flash_attn<4096, 64, 4, 64, 1, 1, 3><<<dim3(4, 64, 4), 256, 0, stream>>>(
      qt, kt, vt, ws + OP3OFF, ws + ML3OFF, attbf);
  combine3<<<4096, 256, 0, stream>>>(ws + OP3OFF, ws + ML3OFF, attbf);

  conv_mfma<<<dim3(32, 4, 4), 256, 0, stream>>>(attbf, w2bf, bo, gamma, beta,
                                                rmean, rvar, out);
}

// Round 8
// 283.570 us; speedup vs baseline: 4.0895x; 1.2705x over previous
//
#include <hip/hip_runtime.h>
#include <math.h>

// Problem constants: b=4, C=256, H=W=64
#define NPOS 4096            // 64*64 spatial positions
#define CPB  1048576         // C*NPOS, per-batch stride in fp32 q/k/v
// ws layout (float offsets)
#define QOFF  ((size_t)0)          // fp32 q; after qk-preps: v_t bf16 (2.097M fl) + ml3 + ml2
#define KOFF  ((size_t)4194304)    // fp32 k; after preps: head3 opart (4.19M fl)
#define VOFF  ((size_t)8388608)    // fp32 v; after preps: h1 spart (2M fl) + head2 opart (2M fl)
#define AOFF  ((size_t)12582912)   // bf16 att, [b][pos][c], 4*4096*256 ushort
#define S0OFF ((size_t)16777216)   // q_t (2.097M fl) + k_t (2.097M fl) + h0 Spart (131K fl)
#define WTOFF ((size_t)21250048)   // bf16 W2 [k][o][c], 9*256*256 ushort
// derived regions
#define QTOFF   S0OFF                      // q_t bf16 all heads: [(b*4+h)*262144] ush
#define KTOFF   (S0OFF + (size_t)2097152)  // k_t bf16
#define SP0OFF  (S0OFF + (size_t)4194304)  // head0 partial S: 4b*8ds*64*64 fp32
#define VTOFF   QOFF                       // v_t bf16 all heads (AFTER qk-preps complete)
#define ML3OFF  (QOFF + (size_t)2097152)   // head3 (m,l): 4*4*4096*2 = 131072 fl
#define ML2OFF  (QOFF + (size_t)2228224)   // head2 (m,l): 4*2*1024*2 = 16384 fl
#define OP3OFF  KOFF                       // head3 partial O: 4*4*4096*64 fl
#define SP1OFF  VOFF                       // h1 partial S: 4b*8ds*256*256 = 2097152 fl
#define OP2OFF  (VOFF + (size_t)2097152)   // head2 partial O: 4*2*1024*256 = 2097152 fl

typedef __attribute__((ext_vector_type(8))) short bf16x8;
typedef __attribute__((ext_vector_type(4))) float f32x4;

static __device__ __forceinline__ unsigned short f2bf(float f) {
  union { float f; unsigned u; } v; v.f = f;
  unsigned u = v.u;
  return (unsigned short)((u + 0x7FFFu + ((u >> 16) & 1u)) >> 16);
}

// ---------------------------------------------------------------------------
// QKV 1x1-conv projections via bf16 MFMA, fp32 out. (proven)
__global__ __launch_bounds__(256) void qkv_mfma(
    const float* __restrict__ x,
    const float* __restrict__ Wq, const float* __restrict__ Wk, const float* __restrict__ Wv,
    const float* __restrict__ bq, const float* __restrict__ bk, const float* __restrict__ bv,
    float* __restrict__ ws) {
  int b = blockIdx.z / 3, t = blockIdx.z % 3;
  const float* W    = (t == 0) ? Wq : (t == 1) ? Wk : Wv;
  const float* bias = (t == 0) ? bq : (t == 1) ? bk : bv;
  float* outp = ws + (size_t)t * 4194304 + (size_t)b * CPB;
  int o0 = blockIdx.y * 64, p0 = blockIdx.x * 64;
  __shared__ unsigned short Wt[64 * 72];
  __shared__ unsigned short Xs[64 * 72];
  int tid = threadIdx.x;
  int wv = tid >> 6, l = tid & 63;
  int lg = l >> 4, ll = l & 15;
  f32x4 acc[4];
#pragma unroll
  for (int mi = 0; mi < 4; ++mi) acc[mi] = (f32x4){0.f, 0.f, 0.f, 0.f};

  int wol = tid >> 2, wcp = (tid & 3) * 16;
  int xcc = tid >> 6, xpz = tid & 63;

  for (int c0 = 0; c0 < 256; c0 += 64) {
    __syncthreads();
#pragma unroll
    for (int u = 0; u < 4; ++u) {
      float4 w4 = *(const float4*)&W[(size_t)(o0 + wol) * 256 + c0 + wcp + u * 4];
      ushort4 pk;
      pk.x = f2bf(w4.x); pk.y = f2bf(w4.y); pk.z = f2bf(w4.z); pk.w = f2bf(w4.w);
      *(ushort4*)&Wt[wol * 72 + wcp + u * 4] = pk;
    }
#pragma unroll
    for (int r = 0; r < 16; ++r) {
      int c = xcc * 16 + r;
      Xs[xpz * 72 + c] = f2bf(x[(size_t)b * CPB + (size_t)(c0 + c) * NPOS + p0 + xpz]);
    }
    __syncthreads();
#pragma unroll
    for (int ks = 0; ks < 2; ++ks) {
      bf16x8 xb = *(const bf16x8*)&Xs[(wv * 16 + ll) * 72 + ks * 32 + lg * 8];
#pragma unroll
      for (int mi = 0; mi < 4; ++mi) {
        bf16x8 wa = *(const bf16x8*)&Wt[(mi * 16 + ll) * 72 + ks * 32 + lg * 8];
        acc[mi] = __builtin_amdgcn_mfma_f32_16x16x32_bf16(wa, xb, acc[mi], 0, 0, 0);
      }
    }
  }
#pragma unroll
  for (int mi = 0; mi < 4; ++mi)
#pragma unroll
    for (int r = 0; r < 4; ++r) {
      int o = o0 + mi * 16 + lg * 4 + r;
      outp[(size_t)o * NPOS + p0 + wv * 16 + ll] = acc[mi][r] + bias[o];
    }
}

// ---------------------------------------------------------------------------
// Prep bodies (proven round 6).
template<int PH, int PW, int HEAD>
__device__ __forceinline__ void qk_body(const float* __restrict__ srcbase,
                                        unsigned short* __restrict__ dstbase) {
  constexpr int PP = PH * PW, D = 64 * PP, OW = 64 / PW;
  int b = blockIdx.y;
  const float* src = srcbase + (size_t)b * CPB + (size_t)HEAD * 64 * NPOS;
  unsigned short* dst = dstbase + ((size_t)b * 4 + HEAD) * 262144;
  int idx = blockIdx.x * 256 + threadIdx.x;
  int t = idx / (D / 8), j8 = idx % (D / 8);
  int po = t / OW, qo = t % OW;
  union { unsigned short u16[8]; uint4 v; } pk;
#pragma unroll
  for (int e = 0; e < 8; ++e) {
    int d = j8 * 8 + e;
    int c = d / PP, rem = d % PP, y = rem / PW, x = rem % PW;
    pk.u16[e] = f2bf(src[(size_t)c * NPOS + (po * PH + y) * 64 + qo * PW + x]);
  }
  *(uint4*)&dst[(size_t)t * D + j8 * 8] = pk.v;
}

template<int PH, int PW, int HEAD>
__device__ __forceinline__ void v_body(const float* __restrict__ vsrc,
                                       unsigned short* __restrict__ vt) {
  constexpr int PP = PH * PW, NT = NPOS / PP, OW = 64 / PW;
  int b = blockIdx.y;
  const float* src = vsrc + (size_t)b * CPB + (size_t)HEAD * 64 * NPOS;
  unsigned short* dst = vt + ((size_t)b * 4 + HEAD) * 262144;
  int idx = blockIdx.x * 256 + threadIdx.x;
  int d = idx / (NT / 8), j8 = idx % (NT / 8);
  int c = d / PP, rem = d % PP, y = rem / PW, x = rem % PW;
  union { unsigned short u16[8]; uint4 v; } pk;
#pragma unroll
  for (int e = 0; e < 8; ++e) {
    int t = j8 * 8 + e;
    int po = t / OW, qo = t % OW;
    pk.u16[e] = f2bf(src[(size_t)c * NPOS + (po * PH + y) * 64 + qo * PW + x]);
  }
  *(uint4*)&dst[(size_t)d * NT + j8 * 8] = pk.v;
}

// head-3 q/k LDS-transpose body (proven). Uses blocks with blockIdx.x < 64 only.
__device__ __forceinline__ void qk3_body(const float* __restrict__ srcbase,
                                         unsigned short* __restrict__ dstbase,
                                         float (*tile)[65]) {
  int pt = blockIdx.x, b = blockIdx.y;
  const float* src = srcbase + (size_t)b * CPB + (size_t)192 * NPOS + pt * 64;
  unsigned short* dst = dstbase + ((size_t)b * 4 + 3) * 262144 + (size_t)pt * 4096;
  int tid = threadIdx.x;
  int a = tid >> 6, pz = tid & 63;
#pragma unroll
  for (int r = 0; r < 16; ++r) {
    int ch = a + r * 4;
    tile[pz][ch] = src[(size_t)ch * NPOS + pz];
  }
  __syncthreads();
  int ch2 = tid & 63, pr = tid >> 6;
#pragma unroll
  for (int r = 0; r < 16; ++r) {
    int pos = pr + r * 4;
    dst[(size_t)pos * 64 + ch2] = f2bf(tile[pos][ch2]);
  }
}

// Launch 1: q/k preps only (reads fp32 q/k; writes q_t/k_t — no aliasing).
// grid (128, 4b, 8): z = {q0,k0,q1,k1,q2,k2,q3,k3}
__global__ __launch_bounds__(256) void prep_qk_all(const float* __restrict__ qf32,
                                                   const float* __restrict__ kf32,
                                                   unsigned short* __restrict__ qt,
                                                   unsigned short* __restrict__ kt_) {
  __shared__ float tile[64][65];
  switch (blockIdx.z) {
    case 0:  qk_body<8, 8, 0>(qf32, qt);  break;
    case 1:  qk_body<8, 8, 0>(kf32, kt_); break;
    case 2:  qk_body<4, 4, 1>(qf32, qt);  break;
    case 3:  qk_body<4, 4, 1>(kf32, kt_); break;
    case 4:  qk_body<2, 2, 2>(qf32, qt);  break;
    case 5:  qk_body<2, 2, 2>(kf32, kt_); break;
    case 6:  if (blockIdx.x < 64) qk3_body(qf32, qt, tile);  break;
    default: if (blockIdx.x < 64) qk3_body(kf32, kt_, tile); break;
  }
}

// Launch 2: v preps (reads fp32 v; writes v_t over now-dead fp32 q region).
// grid (128, 4b, 4): z = {v0,v1,v2,v3}
__global__ __launch_bounds__(256) void prep_v_all(const float* __restrict__ vf32,
                                                  unsigned short* __restrict__ vt) {
  switch (blockIdx.z) {
    case 0:  v_body<8, 8, 0>(vf32, vt); break;
    case 1:  v_body<4, 4, 1>(vf32, vt); break;
    case 2:  v_body<2, 2, 2>(vf32, vt); break;
    default: v_body<1, 1, 3>(vf32, vt); break;
  }
}

// ---------------------------------------------------------------------------
// Generic MFMA flash attention (proven). A row=l&15, k=(l>>4)*8; D col=l&15, row=(l>>4)*4+reg.
template<int NTOK, int DDIM, int NSPLIT, int KVB, int PH, int PW, int HEAD>
__global__ __launch_bounds__(256) void flash_attn(
    const unsigned short* __restrict__ qt, const unsigned short* __restrict__ kt_,
    const unsigned short* __restrict__ vt, float* __restrict__ opart,
    float* __restrict__ ml, unsigned short* __restrict__ attbf) {
  constexpr int KSTR = DDIM + 8;
  constexpr int VSTR = KVB + 8;
  constexpr int NT   = KVB / 16;
  constexpr int KCH  = DDIM / 32;
  constexpr int PKS  = KVB / 32;
  constexpr int OCG  = DDIM / 16;
  constexpr float scale = (DDIM == 64) ? 0.125f : (DDIM == 256) ? 0.0625f
                        : (DDIM == 1024) ? 0.03125f : 0.015625f;
  constexpr int PP = PH * PW, OW = 64 / PW;
  int b = blockIdx.x, q0 = blockIdx.y * 64, split = blockIdx.z;
  const unsigned short* Q = qt + ((size_t)b * 4 + HEAD) * 262144;
  const unsigned short* K = kt_ + ((size_t)b * 4 + HEAD) * 262144;
  const unsigned short* V = vt + ((size_t)b * 4 + HEAD) * 262144;
  __shared__ unsigned short Ks[KVB * KSTR];
  __shared__ unsigned short Vs[DDIM * VSTR];
  __shared__ unsigned short Ps[4][16 * VSTR];
  int tid = threadIdx.x;
  int wv = tid >> 6, l = tid & 63;
  int lg = l >> 4, ll = l & 15;
  int qw = q0 + wv * 16;

  bf16x8 qf[KCH];
#pragma unroll
  for (int kc = 0; kc < KCH; ++kc)
    qf[kc] = *(const bf16x8*)&Q[(size_t)(qw + ll) * DDIM + kc * 32 + lg * 8];

  float m_r[4] = {-3.0e38f, -3.0e38f, -3.0e38f, -3.0e38f};
  float l_r[4] = {0.f, 0.f, 0.f, 0.f};
  f32x4 o_acc[OCG];
#pragma unroll
  for (int c = 0; c < OCG; ++c) o_acc[c] = (f32x4){0.f, 0.f, 0.f, 0.f};

  for (int kt0 = split * (NTOK / NSPLIT); kt0 < (split + 1) * (NTOK / NSPLIT); kt0 += KVB) {
    __syncthreads();
#pragma unroll
    for (int i = 0; i < KVB * DDIM / 2048; ++i) {
      int u = i * 256 + tid;
      int key = u / (DDIM / 8), part = u % (DDIM / 8);
      *(uint4*)&Ks[key * KSTR + part * 8] =
          *(const uint4*)&K[(size_t)(kt0 + key) * DDIM + part * 8];
    }
#pragma unroll
    for (int i = 0; i < KVB * DDIM / 2048; ++i) {
      int u = i * 256 + tid;
      int d = u / (KVB / 8), part = u % (KVB / 8);
      *(uint4*)&Vs[d * VSTR + part * 8] =
          *(const uint4*)&V[(size_t)d * NTOK + kt0 + part * 8];
    }
    __syncthreads();
    f32x4 s_acc[NT];
#pragma unroll
    for (int n = 0; n < NT; ++n) s_acc[n] = (f32x4){0.f, 0.f, 0.f, 0.f};
#pragma unroll
    for (int n = 0; n < NT; ++n)
#pragma unroll
      for (int kc = 0; kc < KCH; ++kc) {
        bf16x8 kf = *(const bf16x8*)&Ks[(n * 16 + ll) * KSTR + kc * 32 + lg * 8];
        s_acc[n] = __builtin_amdgcn_mfma_f32_16x16x32_bf16(qf[kc], kf, s_acc[n], 0, 0, 0);
      }
    float f_r[4];
#pragma unroll
    for (int r = 0; r < 4; ++r) {
      float mx = -3.0e38f;
#pragma unroll
      for (int n = 0; n < NT; ++n) mx = fmaxf(mx, s_acc[n][r]);
      mx *= scale;
#pragma unroll
      for (int d = 8; d >= 1; d >>= 1) mx = fmaxf(mx, __shfl_xor(mx, d));
      float mn = fmaxf(m_r[r], mx);
      f_r[r] = __expf(m_r[r] - mn);
      m_r[r] = mn;
      float rs = 0.f;
#pragma unroll
      for (int n = 0; n < NT; ++n) {
        float p = __expf(s_acc[n][r] * scale - mn);
        s_acc[n][r] = p;
        rs += p;
      }
#pragma unroll
      for (int d = 8; d >= 1; d >>= 1) rs += __shfl_xor(rs, d);
      l_r[r] = l_r[r] * f_r[r] + rs;
#pragma unroll
      for (int c = 0; c < OCG; ++c) o_acc[c][r] *= f_r[r];
    }
#pragma unroll
    for (int r = 0; r < 4; ++r)
#pragma unroll
      for (int n = 0; n < NT; ++n)
        Ps[wv][(lg * 4 + r) * VSTR + n * 16 + ll] = f2bf(s_acc[n][r]);
#pragma unroll
    for (int pk = 0; pk < PKS; ++pk) {
      bf16x8 pa = *(const bf16x8*)&Ps[wv][ll * VSTR + pk * 32 + lg * 8];
#pragma unroll
      for (int c = 0; c < OCG; ++c) {
        bf16x8 vf = *(const bf16x8*)&Vs[(c * 16 + ll) * VSTR + pk * 32 + lg * 8];
        o_acc[c] = __builtin_amdgcn_mfma_f32_16x16x32_bf16(pa, vf, o_acc[c], 0, 0, 0);
      }
    }
  }
  if constexpr (NSPLIT > 1) {
    size_t ob = (size_t)(b * NSPLIT + split) * NTOK;
#pragma unroll
    for (int r = 0; r < 4; ++r) {
      int q = qw + lg * 4 + r;
#pragma unroll
      for (int c = 0; c < OCG; ++c)
        opart[(ob + q) * DDIM + c * 16 + ll] = o_acc[c][r];
      if (ll == 0) {
        ml[(ob + q) * 2]     = m_r[r];
        ml[(ob + q) * 2 + 1] = l_r[r];
      }
    }
  } else {
#pragma unroll
    for (int r = 0; r < 4; ++r) {
      float inv = 1.0f / l_r[r];
      int q = qw + lg * 4 + r;
      int po = q / OW, qo = q % OW;
#pragma unroll
      for (int c = 0; c < OCG; ++c) {
        int d = c * 16 + ll;
        int ch = d / PP, rem = d % PP, y = rem / PW, x = rem % PW;
        int pos = (po * PH + y) * 64 + qo * PW + x;
        attbf[((size_t)b * NPOS + pos) * 256 + HEAD * 64 + ch] = f2bf(o_acc[c][r] * inv);
      }
    }
  }
}

// Merge head-3 split partials -> bf16 att. grid 4096 x 256. (proven)
__global__ __launch_bounds__(256) void combine3(const float* __restrict__ opart,
                                                const float* __restrict__ ml,
                                                unsigned short* __restrict__ attbf) {
  int bid = blockIdx.x;
  int b = bid >> 10, qt4 = bid & 1023;
  int q = qt4 * 4 + (threadIdx.x >> 6), ch = threadIdx.x & 63;
  float ms[4], ls[4];
  float M = -3.0e38f;
#pragma unroll
  for (int s = 0; s < 4; ++s) {
    size_t r = ((size_t)(b * 4 + s) * 4096 + q) * 2;
    ms[s] = ml[r]; ls[s] = ml[r + 1];
    M = fmaxf(M, ms[s]);
  }
  float num = 0.f, den = 0.f;
#pragma unroll
  for (int s = 0; s < 4; ++s) {
    float w = __expf(ms[s] - M);
    num += w * opart[((size_t)(b * 4 + s) * 4096 + q) * 64 + ch];
    den += w * ls[s];
  }
  attbf[((size_t)b * 4096 + q) * 256 + 192 + ch] = f2bf(num / den);
}

// Merge head-2 split partials (NSPLIT=2). grid (4b*1024 q) x 256 (d).
__global__ __launch_bounds__(256) void combine2(const float* __restrict__ opart,
                                                const float* __restrict__ ml,
                                                unsigned short* __restrict__ attbf) {
  int bid = blockIdx.x;
  int b = bid >> 10, q = bid & 1023;
  int d = threadIdx.x;
  float ms[2], ls[2];
  float M = -3.0e38f;
#pragma unroll
  for (int s = 0; s < 2; ++s) {
    size_t r = ((size_t)(b * 2 + s) * 1024 + q) * 2;
    ms[s] = ml[r]; ls[s] = ml[r + 1];
    M = fmaxf(M, ms[s]);
  }
  float num = 0.f, den = 0.f;
#pragma unroll
  for (int s = 0; s < 2; ++s) {
    float w = __expf(ms[s] - M);
    num += w * opart[((size_t)(b * 2 + s) * 1024 + q) * 256 + d];
    den += w * ls[s];
  }
  int c = d >> 2, rem = d & 3, y = rem >> 1, x = rem & 1;
  int po = q >> 5, qo = q & 31;
  int pos = (po * 2 + y) * 64 + qo * 2 + x;
  attbf[((size_t)b * NPOS + pos) * 256 + 128 + c] = f2bf(num / den);
}

// ---------------------------------------------------------------------------
// Head 0 (n=64, D=4096): partial-S kernel. grid (4b, 8 d-slices). (proven)
__global__ __launch_bounds__(256) void h0_score(const unsigned short* __restrict__ qt,
                                                const unsigned short* __restrict__ kt_,
                                                float* __restrict__ spart) {
  int b = blockIdx.x, ds = blockIdx.y;
  const unsigned short* Q = qt + ((size_t)b * 4 + 0) * 262144;
  const unsigned short* K = kt_ + ((size_t)b * 4 + 0) * 262144;
  __shared__ unsigned short Qc[64 * 72], Kc[64 * 72];
  int tid = threadIdx.x;
  int wv = tid >> 6, l = tid & 63;
  int lg = l >> 4, ll = l & 15;
  f32x4 s_acc[4];
#pragma unroll
  for (int n = 0; n < 4; ++n) s_acc[n] = (f32x4){0.f, 0.f, 0.f, 0.f};
  for (int ch = 0; ch < 8; ++ch) {
    int d0 = ds * 512 + ch * 64;
    __syncthreads();
#pragma unroll
    for (int i = 0; i < 2; ++i) {
      int u = i * 256 + tid, row = u >> 3, part = u & 7;
      *(uint4*)&Qc[row * 72 + part * 8] = *(const uint4*)&Q[(size_t)row * 4096 + d0 + part * 8];
      *(uint4*)&Kc[row * 72 + part * 8] = *(const uint4*)&K[(size_t)row * 4096 + d0 + part * 8];
    }
    __syncthreads();
#pragma unroll
    for (int n = 0; n < 4; ++n)
#pragma unroll
      for (int ks = 0; ks < 2; ++ks) {
        bf16x8 qa = *(const bf16x8*)&Qc[(wv * 16 + ll) * 72 + ks * 32 + lg * 8];
        bf16x8 kf = *(const bf16x8*)&Kc[(n * 16 + ll) * 72 + ks * 32 + lg * 8];
        s_acc[n] = __builtin_amdgcn_mfma_f32_16x16x32_bf16(qa, kf, s_acc[n], 0, 0, 0);
      }
  }
#pragma unroll
  for (int n = 0; n < 4; ++n)
#pragma unroll
    for (int r = 0; r < 4; ++r)
      spart[(((size_t)b * 8 + ds) * 64 + (wv * 16 + lg * 4 + r)) * 64 + n * 16 + ll] =
          s_acc[n][r];
}

// Head 0 finish: sum partials, exact softmax, PV over 512-d slice. (proven)
__global__ __launch_bounds__(256) void h0_pv(const float* __restrict__ spart,
                                             const unsigned short* __restrict__ vt,
                                             unsigned short* __restrict__ attbf) {
  int b = blockIdx.x, ds = blockIdx.y;
  const unsigned short* V = vt + ((size_t)b * 4 + 0) * 262144;
  __shared__ float S[64 * 65];
  __shared__ unsigned short Ps[64 * 72];
  __shared__ unsigned short Vc[64 * 72];
  int tid = threadIdx.x;
  int wv = tid >> 6, l = tid & 63;
  int lg = l >> 4, ll = l & 15;
#pragma unroll
  for (int i = 0; i < 16; ++i) {
    int idx = i * 256 + tid, q = idx >> 6, k = idx & 63;
    float s = 0.f;
#pragma unroll
    for (int sl = 0; sl < 8; ++sl)
      s += spart[(((size_t)b * 8 + sl) * 64 + q) * 64 + k];
    S[q * 65 + k] = s;
  }
  __syncthreads();
  for (int rr = 0; rr < 16; ++rr) {
    int row = wv * 16 + rr;
    float v = S[row * 65 + l] * 0.015625f;
    float m = v;
#pragma unroll
    for (int d = 32; d >= 1; d >>= 1) m = fmaxf(m, __shfl_xor(m, d));
    float p = __expf(v - m);
    float su = p;
#pragma unroll
    for (int d = 32; d >= 1; d >>= 1) su += __shfl_xor(su, d);
    Ps[row * 72 + l] = f2bf(p / su);
  }
  __syncthreads();
  for (int ch = 0; ch < 8; ++ch) {
    int d0 = ds * 512 + ch * 64;
    __syncthreads();
#pragma unroll
    for (int i = 0; i < 2; ++i) {
      int u = i * 256 + tid, row = u >> 3, part = u & 7;
      *(uint4*)&Vc[row * 72 + part * 8] =
          *(const uint4*)&V[(size_t)(d0 + row) * 64 + part * 8];
    }
    __syncthreads();
    f32x4 o[4];
#pragma unroll
    for (int cg = 0; cg < 4; ++cg) o[cg] = (f32x4){0.f, 0.f, 0.f, 0.f};
#pragma unroll
    for (int cg = 0; cg < 4; ++cg)
#pragma unroll
      for (int ks = 0; ks < 2; ++ks) {
        bf16x8 pa = *(const bf16x8*)&Ps[(wv * 16 + ll) * 72 + ks * 32 + lg * 8];
        bf16x8 vf = *(const bf16x8*)&Vc[(cg * 16 + ll) * 72 + ks * 32 + lg * 8];
        o[cg] = __builtin_amdgcn_mfma_f32_16x16x32_bf16(pa, vf, o[cg], 0, 0, 0);
      }
#pragma unroll
    for (int cg = 0; cg < 4; ++cg)
#pragma unroll
      for (int r = 0; r < 4; ++r) {
        int q = wv * 16 + lg * 4 + r;
        int d = d0 + cg * 16 + ll;
        int c = d >> 6, rem = d & 63, y = rem >> 3, x = rem & 7;
        int po = q >> 3, qo = q & 7;
        int pos = (po * 8 + y) * 64 + qo * 8 + x;
        attbf[((size_t)b * NPOS + pos) * 256 + c] = f2bf(o[cg][r]);
      }
  }
}

// ---------------------------------------------------------------------------
// Head 1 (n=256, D=1024) two-phase. Phase A: partial S. grid (4b, 4qt, 8ds).
__global__ __launch_bounds__(256) void h1_score(const unsigned short* __restrict__ qt,
                                                const unsigned short* __restrict__ kt_,
                                                float* __restrict__ spart) {
  int b = blockIdx.x, qtile = blockIdx.y, ds = blockIdx.z;
  int q0 = qtile * 64, dbase = ds * 128;
  const unsigned short* Q = qt + ((size_t)b * 4 + 1) * 262144;
  const unsigned short* K = kt_ + ((size_t)b * 4 + 1) * 262144;
  __shared__ unsigned short Qc[64 * 72];
  __shared__ unsigned short Kc[256 * 72];
  int tid = threadIdx.x;
  int wv = tid >> 6, l = tid & 63;
  int lg = l >> 4, ll = l & 15;
  f32x4 s_acc[16];
#pragma unroll
  for (int n = 0; n < 16; ++n) s_acc[n] = (f32x4){0.f, 0.f, 0.f, 0.f};
  for (int dc = 0; dc < 2; ++dc) {
    int d0 = dbase + dc * 64;
    __syncthreads();
#pragma unroll
    for (int i = 0; i < 2; ++i) {
      int u = i * 256 + tid, row = u >> 3, part = u & 7;
      *(uint4*)&Qc[row * 72 + part * 8] =
          *(const uint4*)&Q[(size_t)(q0 + row) * 1024 + d0 + part * 8];
    }
#pragma unroll
    for (int i = 0; i < 8; ++i) {
      int u = i * 256 + tid, row = u >> 3, part = u & 7;
      *(uint4*)&Kc[row * 72 + part * 8] =
          *(const uint4*)&K[(size_t)row * 1024 + d0 + part * 8];
    }
    __syncthreads();
#pragma unroll
    for (int ks = 0; ks < 2; ++ks) {
      bf16x8 qa = *(const bf16x8*)&Qc[(wv * 16 + ll) * 72 + ks * 32 + lg * 8];
#pragma unroll
      for (int n = 0; n < 16; ++n) {
        bf16x8 kf = *(const bf16x8*)&Kc[(n * 16 + ll) * 72 + ks * 32 + lg * 8];
        s_acc[n] = __builtin_amdgcn_mfma_f32_16x16x32_bf16(qa, kf, s_acc[n], 0, 0, 0);
      }
    }
  }
#pragma unroll
  for (int n = 0; n < 16; ++n)
#pragma unroll
    for (int r = 0; r < 4; ++r) {
      int q = q0 + wv * 16 + lg * 4 + r;
      spart[(((size_t)b * 8 + ds) * 256 + q) * 256 + n * 16 + ll] = s_acc[n][r];
    }
}

// Phase B: sum partials, exact softmax, PV over 128-d slice. grid (4b, 4qt, 8vs).
__global__ __launch_bounds__(256) void h1_pv(const float* __restrict__ spart,
                                             const unsigned short* __restrict__ vt,
                                             unsigned short* __restrict__ attbf) {
  int b = blockIdx.x, qtile = blockIdx.y, vs = blockIdx.z;
  int q0 = qtile * 64, dv0 = vs * 128;
  const unsigned short* V = vt + ((size_t)b * 4 + 1) * 262144;   // [1024 d][256 n]
  __shared__ unsigned short Ps[64 * 264];
  __shared__ unsigned short Vs[32 * 264];
  int tid = threadIdx.x;
  int wv = tid >> 6, l = tid & 63;
  int lg = l >> 4, ll = l & 15;
  for (int rr = 0; rr < 16; ++rr) {
    int row = q0 + wv * 16 + rr;
    float sv[4];
#pragma unroll
    for (int c4 = 0; c4 < 4; ++c4) {
      float s = 0.f;
#pragma unroll
      for (int sl = 0; sl < 8; ++sl)
        s += spart[(((size_t)b * 8 + sl) * 256 + row) * 256 + c4 * 64 + l];
      sv[c4] = s * 0.03125f;
    }
    float m = fmaxf(fmaxf(sv[0], sv[1]), fmaxf(sv[2], sv[3]));
#pragma unroll
    for (int d = 32; d >= 1; d >>= 1) m = fmaxf(m, __shfl_xor(m, d));
    float p[4], su = 0.f;
#pragma unroll
    for (int c4 = 0; c4 < 4; ++c4) { p[c4] = __expf(sv[c4] - m); su += p[c4]; }
#pragma unroll
    for (int d = 32; d >= 1; d >>= 1) su += __shfl_xor(su, d);
    float inv = 1.0f / su;
#pragma unroll
    for (int c4 = 0; c4 < 4; ++c4)
      Ps[(wv * 16 + rr) * 264 + c4 * 64 + l] = f2bf(p[c4] * inv);
  }
  for (int vc = 0; vc < 4; ++vc) {
    int d0 = dv0 + vc * 32;
    __syncthreads();
#pragma unroll
    for (int i = 0; i < 4; ++i) {
      int u = i * 256 + tid, row = u >> 5, part = u & 31;
      *(uint4*)&Vs[row * 264 + part * 8] =
          *(const uint4*)&V[(size_t)(d0 + row) * 256 + part * 8];
    }
    __syncthreads();
    f32x4 o[2];
    o[0] = (f32x4){0.f, 0.f, 0.f, 0.f};
    o[1] = (f32x4){0.f, 0.f, 0.f, 0.f};
#pragma unroll
    for (int ks = 0; ks < 8; ++ks) {
      bf16x8 pa = *(const bf16x8*)&Ps[(wv * 16 + ll) * 264 + ks * 32 + lg * 8];
#pragma unroll
      for (int cg = 0; cg < 2; ++cg) {
        bf16x8 vf = *(const bf16x8*)&Vs[(cg * 16 + ll) * 264 + ks * 32 + lg * 8];
        o[cg] = __builtin_amdgcn_mfma_f32_16x16x32_bf16(pa, vf, o[cg], 0, 0, 0);
      }
    }
#pragma unroll
    for (int cg = 0; cg < 2; ++cg)
#pragma unroll
      for (int r = 0; r < 4; ++r) {
        int q = q0 + wv * 16 + lg * 4 + r;
        int d = d0 + cg * 16 + ll;
        int c = d >> 4, rem = d & 15, y = rem >> 2, x = rem & 3;
        int po = q >> 4, qo = q & 15;
        int pos = (po * 4 + y) * 64 + qo * 4 + x;
        attbf[((size_t)b * NPOS + pos) * 256 + 64 + c] = f2bf(o[cg][r]);
      }
  }
}

// ---------------------------------------------------------------------------
// Wo [o][c][ky][kx] fp32 -> W2 [k=ky*3+kx][o][c] bf16
__global__ __launch_bounds__(256) void transpose_wo_bf(const float* __restrict__ Wo,
                                                       unsigned short* __restrict__ W2) {
  int idx = blockIdx.x * 256 + threadIdx.x;
  int o = idx / 2304, r = idx % 2304;
  int c = r / 9, k = r % 9;
  W2[(size_t)k * 65536 + (size_t)o * 256 + c] = f2bf(Wo[idx]);
}

// 3x3 SAME conv (bf16 MFMA implicit GEMM) + BN + LeakyReLU(0.2). (proven)
__global__ __launch_bounds__(256) void conv_mfma(
    const unsigned short* __restrict__ attbf, const unsigned short* __restrict__ w2,
    const float* __restrict__ bo, const float* __restrict__ gamma,
    const float* __restrict__ beta, const float* __restrict__ rmean,
    const float* __restrict__ rvar, float* __restrict__ out) {
  int hp = blockIdx.x, ot = blockIdx.y, b = blockIdx.z;
  int h0 = hp * 2, o0 = ot * 64;
  __shared__ unsigned short As[2 * 66 * 72];
  __shared__ unsigned short Ws[3 * 64 * 72];
  int tid = threadIdx.x;
  int wi = tid >> 6, l = tid & 63;
  int hrow = wi >> 1, wseg = wi & 1;
  int lg = l >> 4, ll = l & 15;
  const size_t attb = (size_t)b * NPOS * 256;
  f32x4 acc[4][2];
#pragma unroll
  for (int mi = 0; mi < 4; ++mi)
#pragma unroll
    for (int ni = 0; ni < 2; ++ni) acc[mi][ni] = (f32x4){0.f, 0.f, 0.f, 0.f};

  for (int dy = 0; dy < 3; ++dy) {
    for (int c0 = 0; c0 < 256; c0 += 64) {
      __syncthreads();
      if (tid < 128) {
        int rowl = tid >> 6, w = tid & 63;
        int ghh = h0 + dy - 1 + rowl;
        uint4 z = make_uint4(0u, 0u, 0u, 0u);
        uint4 a[8];
        if (ghh >= 0 && ghh < 64) {
          const uint4* src = (const uint4*)(attbf + attb + ((size_t)(ghh * 64 + w) * 256 + c0));
#pragma unroll
          for (int q = 0; q < 8; ++q) a[q] = src[q];
        } else {
#pragma unroll
          for (int q = 0; q < 8; ++q) a[q] = z;
        }
        uint4* dst = (uint4*)&As[(rowl * 66 + 1 + w) * 72];
#pragma unroll
        for (int q = 0; q < 8; ++q) dst[q] = a[q];
        if (w == 0 || w == 63) {
          uint4* dz = (uint4*)&As[(rowl * 66 + ((w == 0) ? 0 : 65)) * 72];
#pragma unroll
          for (int q = 0; q < 8; ++q) dz[q] = z;
        }
      }
      if (tid >= 64) {
        int p = tid - 64;
        int dx = p >> 6, ol = p & 63;
        const uint4* src = (const uint4*)(w2 + ((size_t)(dy * 3 + dx) * 65536 +
                                                (size_t)(o0 + ol) * 256 + c0));
        uint4* dst = (uint4*)&Ws[(dx * 64 + ol) * 72];
#pragma unroll
        for (int q = 0; q < 8; ++q) dst[q] = src[q];
      }
      __syncthreads();
#pragma unroll
      for (int dx = 0; dx < 3; ++dx) {
#pragma unroll
        for (int ks = 0; ks < 2; ++ks) {
          bf16x8 af[4];
#pragma unroll
          for (int mi = 0; mi < 4; ++mi)
            af[mi] = *(const bf16x8*)&Ws[(dx * 64 + mi * 16 + ll) * 72 + ks * 32 + lg * 8];
#pragma unroll
          for (int ni = 0; ni < 2; ++ni) {
            bf16x8 bfr = *(const bf16x8*)&As[(hrow * 66 + wseg * 32 + ni * 16 + ll + dx) * 72 +
                                             ks * 32 + lg * 8];
#pragma unroll
            for (int mi = 0; mi < 4; ++mi)
              acc[mi][ni] = __builtin_amdgcn_mfma_f32_16x16x32_bf16(af[mi], bfr, acc[mi][ni],
                                                                    0, 0, 0);
          }
        }
      }
    }
  }
  int h = h0 + hrow;
#pragma unroll
  for (int mi = 0; mi < 4; ++mi) {
#pragma unroll
    for (int r = 0; r < 4; ++r) {
      int o = o0 + mi * 16 + lg * 4 + r;
      float g  = gamma[o] * rsqrtf(rvar[o] + 1e-5f);
      float bb = (bo[o] - rmean[o]) * g + beta[o];
#pragma unroll
      for (int ni = 0; ni < 2; ++ni) {
        float zv = acc[mi][ni][r] * g + bb;
        zv = (zv >= 0.f) ? zv : 0.2f * zv;
        out[((size_t)(b * 256 + o)) * NPOS + h * 64 + wseg * 32 + ni * 16 + ll] = zv;
      }
    }
  }
}

// ---------------------------------------------------------------------------
extern "C" void kernel_launch(void* const* d_in, const int* in_sizes, int n_in,
                              void* d_out, int out_size, void* d_ws, size_t ws_size,
                              hipStream_t stream) {
  (void)in_sizes; (void)n_in; (void)out_size; (void)ws_size;
  const float* x     = (const float*)d_in[0];
  const float* Wq    = (const float*)d_in[1];
  const float* bq    = (const float*)d_in[2];
  const float* Wk    = (const float*)d_in[3];
  const float* bk    = (const float*)d_in[4];
  const float* Wv    = (const float*)d_in[5];
  const float* bv    = (const float*)d_in[6];
  const float* Wo    = (const float*)d_in[7];
  const float* bo    = (const float*)d_in[8];
  const float* gamma = (const float*)d_in[9];
  const float* beta  = (const float*)d_in[10];
  const float* rmean = (const float*)d_in[11];
  const float* rvar  = (const float*)d_in[12];
  float* ws  = (float*)d_ws;
  float* out = (float*)d_out;
  unsigned short* attbf = (unsigned short*)(ws + AOFF);
  unsigned short* w2bf  = (unsigned short*)(ws + WTOFF);
  unsigned short* qt    = (unsigned short*)(ws + QTOFF);
  unsigned short* kt    = (unsigned short*)(ws + KTOFF);
  unsigned short* vt    = (unsigned short*)(ws + VTOFF);
  const float* qf32 = ws + QOFF;
  const float* kf32 = ws + KOFF;
  const float* vf32 = ws + VOFF;

  transpose_wo_bf<<<2304, 256, 0, stream>>>(Wo, w2bf);
  qkv_mfma<<<dim3(64, 4, 12), 256, 0, stream>>>(x, Wq, Wk, Wv, bq, bk, bv, ws);

  // q/k preps first (read fp32 q); then v preps (overwrite dead fp32 q with v_t).
  // Two launches restore the write-after-read ordering the round-7 fusion broke.
  prep_qk_all<<<dim3(128, 4, 8), 256, 0, stream>>>(qf32, kf32, qt, kt);
  prep_v_all<<<dim3(128, 4, 4), 256, 0, stream>>>(vf32, vt);

  // head 0: partial-S + finish
  h0_score<<<dim3(4, 8), 256, 0, stream>>>(qt, kt, ws + SP0OFF);
  h0_pv<<<dim3(4, 8), 256, 0, stream>>>(ws + SP0OFF, vt, attbf);
  // head 1: partial-S (dead fp32 v region) + finish
  h1_score<<<dim3(4, 4, 8), 256, 0, stream>>>(qt, kt, ws + SP1OFF);
  h1_pv<<<dim3(4, 4, 8), 256, 0, stream>>>(ws + SP1OFF, vt, attbf);
  // head 2: split-KV flash (2 splits) + combine
  flash_attn<1024, 256, 2, 32, 2, 2, 2><<<dim3(4, 16, 2), 256, 0, stream>>>(
      qt, kt, vt, ws + OP2OFF, ws + ML2OFF, attbf);
  combine2<<<4096, 256, 0, stream>>>(ws + OP2OFF, ws + ML2OFF, attbf);
  // head 3: split-KV flash (4 splits, partials in dead fp32 k region) + combine
  flash_attn<4096, 64, 4, 64, 1, 1, 3><<<dim3(4, 64, 4), 256, 0, stream>>>(
      qt, kt, vt, ws + OP3OFF, ws + ML3OFF, attbf);
  combine3<<<4096, 256, 0, stream>>>(ws + OP3OFF, ws + ML3OFF, attbf);

  conv_mfma<<<dim3(32, 4, 4), 256, 0, stream>>>(attbf, w2bf, bo, gamma, beta,
                                                rmean, rvar, out);
}